// Round 5
// baseline (957.724 us; speedup 1.0000x reference)
//
#include <hip/hip_runtime.h>
#include <hip/hip_bf16.h>
#include <math.h>

#define B_ 8
#define N_ 384
#define F_ 64
#define H_ 128
#define LN_EPS 1e-5f
#define NCHUNK 72          // N_*N_ / 2048

typedef _Float16 f16;
typedef f16 f16x8 __attribute__((ext_vector_type(8)));
typedef float f32x4v __attribute__((ext_vector_type(4)));

// -------------------- setup kernels --------------------

// W2hT[n][k] = fp16( 0.5 * sum_f vW2[k,f] * sW1[f,n] )   (128x128, TRANSPOSED for MFMA A)
__global__ void k_prep_w2p(const float* __restrict__ vW2, const float* __restrict__ sW1,
                           unsigned short* __restrict__ W2hT) {
    int idx = blockIdx.x * 256 + threadIdx.x;   // 0..16383
    int k = idx >> 7, n = idx & 127;
    float acc = 0.f;
#pragma unroll
    for (int f = 0; f < F_; ++f) acc = fmaf(vW2[k * F_ + f], sW1[f * H_ + n], acc);
    f16 hv = (f16)(0.5f * acc);
    W2hT[n * H_ + k] = *reinterpret_cast<unsigned short*>(&hv);
}

// t[row][n] = sum_f (0.25*(in[row,f]+vb2[f])) * sW1[f,n] + 0.5*sb1[n]
__global__ void k_prep_t(const float* __restrict__ inp, const float* __restrict__ sW1,
                         const float* __restrict__ vb2, const float* __restrict__ sb1,
                         float* __restrict__ t) {
    int row = blockIdx.x;
    int n = threadIdx.x;
    float acc = 0.f;
#pragma unroll
    for (int f = 0; f < F_; ++f)
        acc = fmaf(0.25f * (inp[row * F_ + f] + vb2[f]), sW1[f * H_ + n], acc);
    t[row * H_ + n] = acc + 0.5f * sb1[n];
}

// -------------------- phase 1: scores (barrier-free 1-wave workers) --------------------
// Block = 1 wave (64 threads). Owns (b, 2 i-rows), loops 24 j-tiles of 8 -> 16 pairs/tile.
// A-frags of W'^T held in 128 VGPRs (loaded once). Per tile:
//   issue ti/tj loads -> phase A (relu(LN(..)) -> 4KB wave-private LDS, swizzled)
//   -> acc init = ti+tj -> 4x(ds_read bF + 8 MFMA) -> relu(acc)*sW2 -> 2-shfl reduce -> score.
// No __syncthreads anywhere (LDS is wave-private; same-wave lgkmcnt orders write->read).
__global__ __launch_bounds__(64, 2) void k_scores(
    const float* __restrict__ pos, const float* __restrict__ vW1,
    const float* __restrict__ vb1, const float* __restrict__ vg,
    const float* __restrict__ vbeta, const unsigned short* __restrict__ W2hT,
    const float* __restrict__ t, const float* __restrict__ sW2,
    const float* __restrict__ sb2, float* __restrict__ scores) {
    __shared__ __align__(16) char smem[4096];    // rht[16 pairs][256B], swizzled

    const int lane = threadIdx.x;                // 0..63
    const int b = blockIdx.z;
    const int i0 = blockIdx.y * 2;               // 2 i-rows per block
    const int jt0 = blockIdx.x * 24;             // 24 j-tiles per block

    const int ln = lane & 15, h4 = lane >> 4;    // MFMA lane coords

    // ---- A-fragments: W'^T rows, 8 mf x 4 kc, 128 VGPR, loaded once ----
    f16x8 aF[8][4];
#pragma unroll
    for (int mf = 0; mf < 8; ++mf)
#pragma unroll
        for (int kc = 0; kc < 4; ++kc)
            aF[mf][kc] = *(const f16x8*)(W2hT + (mf * 16 + ln) * H_ + kc * 32 + h4 * 8);

    // ---- sW2 fragment (lane's 32 n-values), 32 VGPR, fixed ----
    float4 sw2r[8];
#pragma unroll
    for (int mf = 0; mf < 8; ++mf)
        sw2r[mf] = *(const float4*)(sW2 + mf * 16 + h4 * 4);
    const float sb2v = sb2[0];

    // ---- phase-A lane roles (fixed): pair pA = lane>>2, dim group lA = lane&3 ----
    const int pA = lane >> 2, lA = lane & 3;
    const int d0 = lA * 32;
    const float* piA = pos + (size_t)(b * N_ + i0 + (pA >> 3)) * 3;
    const float axA = piA[0], ayA = piA[1], azA = piA[2];
    const int wbyteA = pA * 256;                 // rht row base
    const int pswA = (pA & 7) << 4;

    // phase-C row addresses
    const int iC = i0 + (ln >> 3);
    const float* tiBase = t + (size_t)(b * N_ + iC) * H_ + h4 * 4;
    float* scoreRow = scores + (size_t)(b * N_ + iC) * N_;

    for (int jt = jt0; jt < jt0 + 24; ++jt) {
        const int j0 = jt * 8;

        // ---- issue t loads early (hidden under phase A) ----
        const float* tjBase = t + (size_t)(b * N_ + j0 + (ln & 7)) * H_ + h4 * 4;
        float4 ti[8], tj[8];
#pragma unroll
        for (int mf = 0; mf < 8; ++mf) {
            ti[mf] = *(const float4*)(tiBase + mf * 16);
            tj[mf] = *(const float4*)(tjBase + mf * 16);
        }

        // ---- Phase A: 4 lanes per pair, 32 dims each -> LDS fp16 ----
        {
            const float* pj = pos + (size_t)(b * N_ + j0 + (pA & 7)) * 3;
            float bx = pj[0], by = pj[1], bz = pj[2];
            float dotv = axA * bx + ayA * by + azA * bz;
            float cx = ayA * bz - azA * by;
            float cy = azA * bx - axA * bz;
            float cz = axA * by - ayA * bx;
            float cn = sqrtf(cx * cx + cy * cy + cz * cz);

            float h[32];
            float s1 = 0.f, s2 = 0.f;
#pragma unroll
            for (int s = 0; s < 8; ++s) {
                float4 wa = *(const float4*)(vW1 + d0 + s * 4);
                float4 wb = *(const float4*)(vW1 + H_ + d0 + s * 4);
                float4 bv = *(const float4*)(vb1 + d0 + s * 4);
                float v;
                v = fmaf(dotv, wa.x, fmaf(cn, wb.x, bv.x)); h[s*4+0] = v; s1 += v; s2 = fmaf(v, v, s2);
                v = fmaf(dotv, wa.y, fmaf(cn, wb.y, bv.y)); h[s*4+1] = v; s1 += v; s2 = fmaf(v, v, s2);
                v = fmaf(dotv, wa.z, fmaf(cn, wb.z, bv.z)); h[s*4+2] = v; s1 += v; s2 = fmaf(v, v, s2);
                v = fmaf(dotv, wa.w, fmaf(cn, wb.w, bv.w)); h[s*4+3] = v; s1 += v; s2 = fmaf(v, v, s2);
            }
            s1 += __shfl_xor(s1, 1); s1 += __shfl_xor(s1, 2);
            s2 += __shfl_xor(s2, 1); s2 += __shfl_xor(s2, 2);
            float mu = s1 * (1.f / 128.f);
            float var = s2 * (1.f / 128.f) - mu * mu;
            float rstd = rsqrtf(var + LN_EPS);
#pragma unroll
            for (int s = 0; s < 4; ++s) {
                float4 g0 = *(const float4*)(vg + d0 + s * 8);
                float4 g1 = *(const float4*)(vg + d0 + s * 8 + 4);
                float4 e0 = *(const float4*)(vbeta + d0 + s * 8);
                float4 e1 = *(const float4*)(vbeta + d0 + s * 8 + 4);
                f16x8 pk;
                pk[0] = (f16)fmaxf(fmaf((h[s*8+0] - mu) * rstd, g0.x, e0.x), 0.f);
                pk[1] = (f16)fmaxf(fmaf((h[s*8+1] - mu) * rstd, g0.y, e0.y), 0.f);
                pk[2] = (f16)fmaxf(fmaf((h[s*8+2] - mu) * rstd, g0.z, e0.z), 0.f);
                pk[3] = (f16)fmaxf(fmaf((h[s*8+3] - mu) * rstd, g0.w, e0.w), 0.f);
                pk[4] = (f16)fmaxf(fmaf((h[s*8+4] - mu) * rstd, g1.x, e1.x), 0.f);
                pk[5] = (f16)fmaxf(fmaf((h[s*8+5] - mu) * rstd, g1.y, e1.y), 0.f);
                pk[6] = (f16)fmaxf(fmaf((h[s*8+6] - mu) * rstd, g1.z, e1.z), 0.f);
                pk[7] = (f16)fmaxf(fmaf((h[s*8+7] - mu) * rstd, g1.w, e1.w), 0.f);
                *(f16x8*)(smem + wbyteA + ((lA * 64 + s * 16) ^ pswA)) = pk;
            }
        }

        // ---- acc init = ti + tj (MFMA C-operand carries the affine part) ----
        f32x4v acc[8];
#pragma unroll
        for (int mf = 0; mf < 8; ++mf) {
            acc[mf][0] = ti[mf].x + tj[mf].x;
            acc[mf][1] = ti[mf].y + tj[mf].y;
            acc[mf][2] = ti[mf].z + tj[mf].z;
            acc[mf][3] = ti[mf].w + tj[mf].w;
        }

        // ---- GEMM: 4 x (1 ds_read_b128 + 8 MFMA), A in registers ----
#pragma unroll
        for (int kc = 0; kc < 4; ++kc) {
            f16x8 bF = *(const f16x8*)(smem + ln * 256 + ((kc * 64 + h4 * 16) ^ ((ln & 7) << 4)));
#pragma unroll
            for (int mf = 0; mf < 8; ++mf)
                acc[mf] = __builtin_amdgcn_mfma_f32_16x16x32_f16(aF[mf][kc], bF, acc[mf], 0, 0, 0);
        }

        // ---- Phase C: relu, dot sW2, reduce over h4 groups ----
        float part = 0.f;
#pragma unroll
        for (int mf = 0; mf < 8; ++mf) {
            part += fmaxf(acc[mf][0], 0.f) * sw2r[mf].x;
            part += fmaxf(acc[mf][1], 0.f) * sw2r[mf].y;
            part += fmaxf(acc[mf][2], 0.f) * sw2r[mf].z;
            part += fmaxf(acc[mf][3], 0.f) * sw2r[mf].w;
        }
        part += __shfl_xor(part, 16);
        part += __shfl_xor(part, 32);
        if (h4 == 0) scoreRow[j0 + (ln & 7)] = part + sb2v;
    }
}

// -------------------- softmax reductions (deterministic trees) --------------------

__global__ void k_pmax(const float* __restrict__ scores, float* __restrict__ pmax) {
    int c = blockIdx.x, b = blockIdx.y;
    int tid = threadIdx.x;
    size_t base = (size_t)b * N_ * N_ + (size_t)c * 2048;
    float m = -1e30f;
#pragma unroll
    for (int s = 0; s < 8; ++s) m = fmaxf(m, scores[base + s * 256 + tid]);
    __shared__ float red[256];
    red[tid] = m;
    __syncthreads();
    for (int st = 128; st > 0; st >>= 1) {
        if (tid < st) red[tid] = fmaxf(red[tid], red[tid + st]);
        __syncthreads();
    }
    if (tid == 0) pmax[b * NCHUNK + c] = red[0];
}

__global__ void k_psum(const float* __restrict__ scores, const float* __restrict__ pmax,
                       float* __restrict__ psum) {
    int c = blockIdx.x, b = blockIdx.y;
    int tid = threadIdx.x;
    __shared__ float gm;
    __shared__ float red[256];
    if (tid == 0) {
        float m = -1e30f;
        for (int k = 0; k < NCHUNK; ++k) m = fmaxf(m, pmax[b * NCHUNK + k]);
        gm = m;
    }
    __syncthreads();
    size_t base = (size_t)b * N_ * N_ + (size_t)c * 2048;
    float s = 0.f;
#pragma unroll
    for (int k = 0; k < 8; ++k) s += expf(scores[base + k * 256 + tid] - gm);
    red[tid] = s;
    __syncthreads();
    for (int st = 128; st > 0; st >>= 1) {
        if (tid < st) red[tid] += red[tid + st];
        __syncthreads();
    }
    if (tid == 0) psum[b * NCHUNK + c] = red[0];
}

// normalize scores -> att in place (one block per (b,i) row)
__global__ void k_att(float* __restrict__ scores, const float* __restrict__ pmax,
                      const float* __restrict__ psum) {
    int i = blockIdx.x, b = blockIdx.y;
    int tid = threadIdx.x;   // 384
    __shared__ float gm, gs;
    if (tid == 0) {
        float m = -1e30f;
        for (int k = 0; k < NCHUNK; ++k) m = fmaxf(m, pmax[b * NCHUNK + k]);
        gm = m;
    } else if (tid == 1) {
        float s = 0.f;
        for (int k = 0; k < NCHUNK; ++k) s += psum[b * NCHUNK + k];
        gs = s;
    }
    __syncthreads();
    size_t idx = (size_t)(b * N_ + i) * N_ + tid;
    scores[idx] = expf(scores[idx] - gm) / gs;
}

// -------------------- phase 2: x --------------------
// One block per (b,i). Recompute relu_h fp32; accH = sum att*relu_h, accI = sum att*in_j,
// s = sum att. x = 0.5*(accH@vW2 + s*vb2) + 0.25*(s*in_i + accI)
__global__ __launch_bounds__(256) void k_x(
    const float* __restrict__ inp, const float* __restrict__ pos,
    const float* __restrict__ vW1, const float* __restrict__ vb1,
    const float* __restrict__ vg, const float* __restrict__ vbeta,
    const float* __restrict__ vW2, const float* __restrict__ vb2,
    const float* __restrict__ att, float* __restrict__ xout) {
    int i = blockIdx.x, b = blockIdx.y;
    int tid = threadIdx.x;
    int jsub = tid >> 3, dg = tid & 7;

    __shared__ float accH[32 * 128];
    __shared__ float accI[32 * 64];
    __shared__ float accS[32];

    float aH[16];
    float aI[8];
#pragma unroll
    for (int dd = 0; dd < 16; ++dd) aH[dd] = 0.f;
#pragma unroll
    for (int ff = 0; ff < 8; ++ff) aI[ff] = 0.f;
    float aS = 0.f;

    const float* pi = pos + (size_t)(b * N_ + i) * 3;
    float ax = pi[0], ay = pi[1], az = pi[2];

    for (int jc = 0; jc < 12; ++jc) {
        int j = jc * 32 + jsub;
        const float* pj = pos + (size_t)(b * N_ + j) * 3;
        float bx = pj[0], by = pj[1], bz = pj[2];
        float dotv = ax * bx + ay * by + az * bz;
        float cx = ay * bz - az * by;
        float cy = az * bx - ax * bz;
        float cz = ax * by - ay * bx;
        float cn = sqrtf(cx * cx + cy * cy + cz * cz);
        float a = att[(size_t)(b * N_ + i) * N_ + j];

        float h[16];
        float s1 = 0.f, s2 = 0.f;
#pragma unroll
        for (int dd = 0; dd < 16; ++dd) {
            int d = dg * 16 + dd;
            float v = fmaf(dotv, vW1[d], fmaf(cn, vW1[H_ + d], vb1[d]));
            h[dd] = v;
            s1 += v;
            s2 = fmaf(v, v, s2);
        }
        s1 += __shfl_xor(s1, 1); s1 += __shfl_xor(s1, 2); s1 += __shfl_xor(s1, 4);
        s2 += __shfl_xor(s2, 1); s2 += __shfl_xor(s2, 2); s2 += __shfl_xor(s2, 4);
        float mu = s1 * (1.f / 128.f);
        float var = s2 * (1.f / 128.f) - mu * mu;
        float rstd = rsqrtf(var + LN_EPS);
#pragma unroll
        for (int dd = 0; dd < 16; ++dd) {
            int d = dg * 16 + dd;
            float v = fmaf((h[dd] - mu) * rstd, vg[d], vbeta[d]);
            aH[dd] = fmaf(a, fmaxf(v, 0.f), aH[dd]);
        }
#pragma unroll
        for (int ff = 0; ff < 8; ++ff) {
            int f = dg * 8 + ff;
            aI[ff] = fmaf(a, inp[(size_t)(b * N_ + j) * F_ + f], aI[ff]);
        }
        if (dg == 0) aS += a;
    }

#pragma unroll
    for (int dd = 0; dd < 16; ++dd) accH[jsub * 128 + dg * 16 + dd] = aH[dd];
#pragma unroll
    for (int ff = 0; ff < 8; ++ff) accI[jsub * 64 + dg * 8 + ff] = aI[ff];
    if (dg == 0) accS[jsub] = aS;
    __syncthreads();

    for (int st = 16; st > 0; st >>= 1) {
        if (jsub < st) {
#pragma unroll
            for (int dd = 0; dd < 16; ++dd)
                accH[jsub * 128 + dg * 16 + dd] += accH[(jsub + st) * 128 + dg * 16 + dd];
#pragma unroll
            for (int ff = 0; ff < 8; ++ff)
                accI[jsub * 64 + dg * 8 + ff] += accI[(jsub + st) * 64 + dg * 8 + ff];
            if (dg == 0) accS[jsub] += accS[jsub + st];
        }
        __syncthreads();
    }

    if (tid < F_) {
        int f = tid;
        float s = accS[0];
        float xv = 0.f;
#pragma unroll
        for (int d = 0; d < H_; ++d) xv = fmaf(accH[d], vW2[d * F_ + f], xv);
        float r = 0.5f * (xv + s * vb2[f]) +
                  0.25f * (s * inp[(size_t)(b * N_ + i) * F_ + f] + accI[f]);
        xout[(size_t)(b * N_ + i) * F_ + f] = r;
    }
}

// -------------------- launch --------------------

extern "C" void kernel_launch(void* const* d_in, const int* in_sizes, int n_in,
                              void* d_out, int out_size, void* d_ws, size_t ws_size,
                              hipStream_t stream) {
    const float* inp   = (const float*)d_in[0];
    const float* pos   = (const float*)d_in[1];
    const float* vW1   = (const float*)d_in[2];
    const float* vb1   = (const float*)d_in[3];
    const float* vg    = (const float*)d_in[4];
    const float* vbeta = (const float*)d_in[5];
    const float* vW2   = (const float*)d_in[6];
    const float* vb2   = (const float*)d_in[7];
    const float* sW1   = (const float*)d_in[8];
    const float* sb1   = (const float*)d_in[9];
    const float* sW2   = (const float*)d_in[10];
    const float* sb2   = (const float*)d_in[11];

    float* xout   = (float*)d_out;                 // B*N*F
    float* attout = xout + B_ * N_ * F_;           // B*N*N (scores -> att in place)

    unsigned short* W2hT = (unsigned short*)d_ws;          // 128*128 fp16 (32KB)
    float* t    = (float*)((char*)d_ws + 32768);           // B*N*128 fp32
    float* pmax = t + B_ * N_ * H_;                        // B*72
    float* psum = pmax + B_ * NCHUNK;                      // B*72

    k_prep_w2p<<<64, 256, 0, stream>>>(vW2, sW1, W2hT);
    k_prep_t<<<B_ * N_, 128, 0, stream>>>(inp, sW1, vb2, sb1, t);
    k_scores<<<dim3(2, 192, B_), 64, 0, stream>>>(
        pos, vW1, vb1, vg, vbeta, W2hT, t, sW2, sb2, attout);
    k_pmax<<<dim3(NCHUNK, B_), 256, 0, stream>>>(attout, pmax);
    k_psum<<<dim3(NCHUNK, B_), 256, 0, stream>>>(attout, pmax, psum);
    k_att<<<dim3(N_, B_), 384, 0, stream>>>(attout, pmax, psum);
    k_x<<<dim3(N_, B_), 256, 0, stream>>>(inp, pos, vW1, vb1, vg, vbeta, vW2, vb2,
                                          attout, xout);
}

// Round 6
// 870.835 us; speedup vs baseline: 1.0998x; 1.0998x over previous
//
#include <hip/hip_runtime.h>
#include <hip/hip_bf16.h>
#include <math.h>

#define B_ 8
#define N_ 384
#define F_ 64
#define H_ 128
#define LN_EPS 1e-5f
#define NCHUNK 72          // N_*N_ / 2048

typedef _Float16 f16;
typedef f16 f16x8 __attribute__((ext_vector_type(8)));
typedef float f32x4v __attribute__((ext_vector_type(4)));

// -------------------- setup kernels --------------------

// W2hT[n][k] = fp16( 0.5 * sum_f vW2[k,f] * sW1[f,n] )   (128x128, TRANSPOSED for MFMA A)
__global__ void k_prep_w2p(const float* __restrict__ vW2, const float* __restrict__ sW1,
                           unsigned short* __restrict__ W2hT) {
    int idx = blockIdx.x * 256 + threadIdx.x;   // 0..16383
    int k = idx >> 7, n = idx & 127;
    float acc = 0.f;
#pragma unroll
    for (int f = 0; f < F_; ++f) acc = fmaf(vW2[k * F_ + f], sW1[f * H_ + n], acc);
    f16 hv = (f16)(0.5f * acc);
    W2hT[n * H_ + k] = *reinterpret_cast<unsigned short*>(&hv);
}

// t[row][n] = sum_f (0.25*(in[row,f]+vb2[f])) * sW1[f,n] + 0.5*sb1[n]
__global__ void k_prep_t(const float* __restrict__ inp, const float* __restrict__ sW1,
                         const float* __restrict__ vb2, const float* __restrict__ sb1,
                         float* __restrict__ t) {
    int row = blockIdx.x;
    int n = threadIdx.x;
    float acc = 0.f;
#pragma unroll
    for (int f = 0; f < F_; ++f)
        acc = fmaf(0.25f * (inp[row * F_ + f] + vb2[f]), sW1[f * H_ + n], acc);
    t[row * H_ + n] = acc + 0.5f * sb1[n];
}

// -------------------- phase 1: scores (persistent 4-wave blocks, LDS A-frags) --------------------
// Block = 256 threads = 4 waves. Stage W' (32KB fp16, swizzled) to LDS ONCE (+1 barrier).
// Wave w owns i-row = blockIdx.x*4 + w; loops 24 j-tiles of 16 pairs, barrier-free,
// wave-private 4KB rht region. Per tile:
//   phase A: relu(LN(inv@vW1+vb1)) -> rht (fp16, swizzled)
//   acc init = ti + tj (MFMA C-operand carries affine part)
//   GEMM: 4 kc x (1 B-read + 8 A-reads ds_read_b128 + 8 MFMA)
//   phase C: relu, dot sW2, 2-shfl reduce -> score
#define RHT_OFF 32768
__global__ __launch_bounds__(256, 3) void k_scores(
    const float* __restrict__ pos, const float* __restrict__ vW1,
    const float* __restrict__ vb1, const float* __restrict__ vg,
    const float* __restrict__ vbeta, const unsigned short* __restrict__ W2hT,
    const float* __restrict__ t, const float* __restrict__ sW2,
    const float* __restrict__ sb2, float* __restrict__ scores) {
    __shared__ __align__(16) char smem[49152];   // 32KB W' + 4 x 4KB rht

    const int tid = threadIdx.x;
    const int b = blockIdx.y;
    const int w = tid >> 6;
    const int lane = tid & 63;
    const int i = blockIdx.x * 4 + w;

    // ---- stage W' once (all 256 threads), swizzled ----
#pragma unroll
    for (int s = 0; s < 8; ++s) {
        int idx = tid + s * 256;                 // 0..2047 16B chunks
        int n = idx >> 4, c = idx & 15;
        uint4 v = *(const uint4*)(W2hT + n * H_ + c * 8);
        *(uint4*)(smem + ((n * 256 + c * 16) ^ ((n & 7) << 4))) = v;
    }
    __syncthreads();

    char* rht = smem + RHT_OFF + w * 4096;

    const int ln = lane & 15, h4 = lane >> 4;    // MFMA lane coords
    const int ksw = (ln & 7) << 4;

    // per-wave fixed data
    const float* pi = pos + (size_t)(b * N_ + i) * 3;
    const float ax = pi[0], ay = pi[1], az = pi[2];

    float4 tiv[8], sw2r[8];
#pragma unroll
    for (int mf = 0; mf < 8; ++mf) {
        tiv[mf]  = *(const float4*)(t + (size_t)(b * N_ + i) * H_ + mf * 16 + h4 * 4);
        sw2r[mf] = *(const float4*)(sW2 + mf * 16 + h4 * 4);
    }
    const float sb2v = sb2[0];

    // phase-A lane roles: pair pA = lane>>2 (j = j0+pA), dim group lA = lane&3
    const int pA = lane >> 2, lA = lane & 3;
    const int d0 = lA * 32;
    const int wbA = pA * 256;
    const int pswA = (pA & 7) << 4;

    float* scoreRow = scores + (size_t)(b * N_ + i) * N_;

    for (int jt = 0; jt < 24; ++jt) {
        const int j0 = jt * 16;

        // ---- Phase A: 4 lanes per pair, 32 dims each -> rht fp16 ----
        {
            const float* pj = pos + (size_t)(b * N_ + j0 + pA) * 3;
            float bx = pj[0], by = pj[1], bz = pj[2];
            float dotv = ax * bx + ay * by + az * bz;
            float cx = ay * bz - az * by;
            float cy = az * bx - ax * bz;
            float cz = ax * by - ay * bx;
            float cn = sqrtf(cx * cx + cy * cy + cz * cz);

            float h[32];
            float s1 = 0.f, s2 = 0.f;
#pragma unroll
            for (int s = 0; s < 8; ++s) {
                float4 wa = *(const float4*)(vW1 + d0 + s * 4);
                float4 wb = *(const float4*)(vW1 + H_ + d0 + s * 4);
                float4 bv = *(const float4*)(vb1 + d0 + s * 4);
                float v;
                v = fmaf(dotv, wa.x, fmaf(cn, wb.x, bv.x)); h[s*4+0] = v; s1 += v; s2 = fmaf(v, v, s2);
                v = fmaf(dotv, wa.y, fmaf(cn, wb.y, bv.y)); h[s*4+1] = v; s1 += v; s2 = fmaf(v, v, s2);
                v = fmaf(dotv, wa.z, fmaf(cn, wb.z, bv.z)); h[s*4+2] = v; s1 += v; s2 = fmaf(v, v, s2);
                v = fmaf(dotv, wa.w, fmaf(cn, wb.w, bv.w)); h[s*4+3] = v; s1 += v; s2 = fmaf(v, v, s2);
            }
            s1 += __shfl_xor(s1, 1); s1 += __shfl_xor(s1, 2);
            s2 += __shfl_xor(s2, 1); s2 += __shfl_xor(s2, 2);
            float mu = s1 * (1.f / 128.f);
            float var = s2 * (1.f / 128.f) - mu * mu;
            float rstd = rsqrtf(var + LN_EPS);
#pragma unroll
            for (int s = 0; s < 4; ++s) {
                float4 g0 = *(const float4*)(vg + d0 + s * 8);
                float4 g1 = *(const float4*)(vg + d0 + s * 8 + 4);
                float4 e0 = *(const float4*)(vbeta + d0 + s * 8);
                float4 e1 = *(const float4*)(vbeta + d0 + s * 8 + 4);
                f16x8 pk;
                pk[0] = (f16)fmaxf(fmaf((h[s*8+0] - mu) * rstd, g0.x, e0.x), 0.f);
                pk[1] = (f16)fmaxf(fmaf((h[s*8+1] - mu) * rstd, g0.y, e0.y), 0.f);
                pk[2] = (f16)fmaxf(fmaf((h[s*8+2] - mu) * rstd, g0.z, e0.z), 0.f);
                pk[3] = (f16)fmaxf(fmaf((h[s*8+3] - mu) * rstd, g0.w, e0.w), 0.f);
                pk[4] = (f16)fmaxf(fmaf((h[s*8+4] - mu) * rstd, g1.x, e1.x), 0.f);
                pk[5] = (f16)fmaxf(fmaf((h[s*8+5] - mu) * rstd, g1.y, e1.y), 0.f);
                pk[6] = (f16)fmaxf(fmaf((h[s*8+6] - mu) * rstd, g1.z, e1.z), 0.f);
                pk[7] = (f16)fmaxf(fmaf((h[s*8+7] - mu) * rstd, g1.w, e1.w), 0.f);
                *(f16x8*)(rht + wbA + ((lA * 64 + s * 16) ^ pswA)) = pk;
            }
        }

        // ---- acc init = ti + tj ----
        f32x4v acc[8];
        const float* tjB = t + (size_t)(b * N_ + j0 + ln) * H_ + h4 * 4;
#pragma unroll
        for (int mf = 0; mf < 8; ++mf) {
            float4 tj = *(const float4*)(tjB + mf * 16);
            acc[mf][0] = tiv[mf].x + tj.x;
            acc[mf][1] = tiv[mf].y + tj.y;
            acc[mf][2] = tiv[mf].z + tj.z;
            acc[mf][3] = tiv[mf].w + tj.w;
        }

        // ---- GEMM: A (W') and B (rht) from LDS ----
#pragma unroll
        for (int kc = 0; kc < 4; ++kc) {
            const int kb = (kc * 64 + h4 * 16) ^ ksw;
            f16x8 bF = *(const f16x8*)(rht + ln * 256 + kb);
#pragma unroll
            for (int mf = 0; mf < 8; ++mf) {
                f16x8 aF = *(const f16x8*)(smem + (mf * 16 + ln) * 256 + kb);
                acc[mf] = __builtin_amdgcn_mfma_f32_16x16x32_f16(aF, bF, acc[mf], 0, 0, 0);
            }
        }

        // ---- Phase C: relu, dot sW2, reduce over h4 groups ----
        float part = 0.f;
#pragma unroll
        for (int mf = 0; mf < 8; ++mf) {
            part += fmaxf(acc[mf][0], 0.f) * sw2r[mf].x;
            part += fmaxf(acc[mf][1], 0.f) * sw2r[mf].y;
            part += fmaxf(acc[mf][2], 0.f) * sw2r[mf].z;
            part += fmaxf(acc[mf][3], 0.f) * sw2r[mf].w;
        }
        part += __shfl_xor(part, 16);
        part += __shfl_xor(part, 32);
        if (h4 == 0) scoreRow[j0 + ln] = part + sb2v;
    }
}

// -------------------- softmax reductions (deterministic trees) --------------------

__global__ void k_pmax(const float* __restrict__ scores, float* __restrict__ pmax) {
    int c = blockIdx.x, b = blockIdx.y;
    int tid = threadIdx.x;
    size_t base = (size_t)b * N_ * N_ + (size_t)c * 2048;
    float m = -1e30f;
#pragma unroll
    for (int s = 0; s < 8; ++s) m = fmaxf(m, scores[base + s * 256 + tid]);
    __shared__ float red[256];
    red[tid] = m;
    __syncthreads();
    for (int st = 128; st > 0; st >>= 1) {
        if (tid < st) red[tid] = fmaxf(red[tid], red[tid + st]);
        __syncthreads();
    }
    if (tid == 0) pmax[b * NCHUNK + c] = red[0];
}

__global__ void k_psum(const float* __restrict__ scores, const float* __restrict__ pmax,
                       float* __restrict__ psum) {
    int c = blockIdx.x, b = blockIdx.y;
    int tid = threadIdx.x;
    __shared__ float gm;
    __shared__ float red[256];
    if (tid == 0) {
        float m = -1e30f;
        for (int k = 0; k < NCHUNK; ++k) m = fmaxf(m, pmax[b * NCHUNK + k]);
        gm = m;
    }
    __syncthreads();
    size_t base = (size_t)b * N_ * N_ + (size_t)c * 2048;
    float s = 0.f;
#pragma unroll
    for (int k = 0; k < 8; ++k) s += expf(scores[base + k * 256 + tid] - gm);
    red[tid] = s;
    __syncthreads();
    for (int st = 128; st > 0; st >>= 1) {
        if (tid < st) red[tid] += red[tid + st];
        __syncthreads();
    }
    if (tid == 0) psum[b * NCHUNK + c] = red[0];
}

// normalize scores -> att in place (one block per (b,i) row)
__global__ void k_att(float* __restrict__ scores, const float* __restrict__ pmax,
                      const float* __restrict__ psum) {
    int i = blockIdx.x, b = blockIdx.y;
    int tid = threadIdx.x;   // 384
    __shared__ float gm, gs;
    if (tid == 0) {
        float m = -1e30f;
        for (int k = 0; k < NCHUNK; ++k) m = fmaxf(m, pmax[b * NCHUNK + k]);
        gm = m;
    } else if (tid == 1) {
        float s = 0.f;
        for (int k = 0; k < NCHUNK; ++k) s += psum[b * NCHUNK + k];
        gs = s;
    }
    __syncthreads();
    size_t idx = (size_t)(b * N_ + i) * N_ + tid;
    scores[idx] = expf(scores[idx] - gm) / gs;
}

// -------------------- phase 2: x --------------------
// One block per (b,i). Recompute relu_h fp32; accH = sum att*relu_h, accI = sum att*in_j,
// s = sum att. x = 0.5*(accH@vW2 + s*vb2) + 0.25*(s*in_i + accI)
__global__ __launch_bounds__(256) void k_x(
    const float* __restrict__ inp, const float* __restrict__ pos,
    const float* __restrict__ vW1, const float* __restrict__ vb1,
    const float* __restrict__ vg, const float* __restrict__ vbeta,
    const float* __restrict__ vW2, const float* __restrict__ vb2,
    const float* __restrict__ att, float* __restrict__ xout) {
    int i = blockIdx.x, b = blockIdx.y;
    int tid = threadIdx.x;
    int jsub = tid >> 3, dg = tid & 7;

    __shared__ float accH[32 * 128];
    __shared__ float accI[32 * 64];
    __shared__ float accS[32];

    float aH[16];
    float aI[8];
#pragma unroll
    for (int dd = 0; dd < 16; ++dd) aH[dd] = 0.f;
#pragma unroll
    for (int ff = 0; ff < 8; ++ff) aI[ff] = 0.f;
    float aS = 0.f;

    const float* pi = pos + (size_t)(b * N_ + i) * 3;
    float ax = pi[0], ay = pi[1], az = pi[2];

    for (int jc = 0; jc < 12; ++jc) {
        int j = jc * 32 + jsub;
        const float* pj = pos + (size_t)(b * N_ + j) * 3;
        float bx = pj[0], by = pj[1], bz = pj[2];
        float dotv = ax * bx + ay * by + az * bz;
        float cx = ay * bz - az * by;
        float cy = az * bx - ax * bz;
        float cz = ax * by - ay * bx;
        float cn = sqrtf(cx * cx + cy * cy + cz * cz);
        float a = att[(size_t)(b * N_ + i) * N_ + j];

        float h[16];
        float s1 = 0.f, s2 = 0.f;
#pragma unroll
        for (int dd = 0; dd < 16; ++dd) {
            int d = dg * 16 + dd;
            float v = fmaf(dotv, vW1[d], fmaf(cn, vW1[H_ + d], vb1[d]));
            h[dd] = v;
            s1 += v;
            s2 = fmaf(v, v, s2);
        }
        s1 += __shfl_xor(s1, 1); s1 += __shfl_xor(s1, 2); s1 += __shfl_xor(s1, 4);
        s2 += __shfl_xor(s2, 1); s2 += __shfl_xor(s2, 2); s2 += __shfl_xor(s2, 4);
        float mu = s1 * (1.f / 128.f);
        float var = s2 * (1.f / 128.f) - mu * mu;
        float rstd = rsqrtf(var + LN_EPS);
#pragma unroll
        for (int dd = 0; dd < 16; ++dd) {
            int d = dg * 16 + dd;
            float v = fmaf((h[dd] - mu) * rstd, vg[d], vbeta[d]);
            aH[dd] = fmaf(a, fmaxf(v, 0.f), aH[dd]);
        }
#pragma unroll
        for (int ff = 0; ff < 8; ++ff) {
            int f = dg * 8 + ff;
            aI[ff] = fmaf(a, inp[(size_t)(b * N_ + j) * F_ + f], aI[ff]);
        }
        if (dg == 0) aS += a;
    }

#pragma unroll
    for (int dd = 0; dd < 16; ++dd) accH[jsub * 128 + dg * 16 + dd] = aH[dd];
#pragma unroll
    for (int ff = 0; ff < 8; ++ff) accI[jsub * 64 + dg * 8 + ff] = aI[ff];
    if (dg == 0) accS[jsub] = aS;
    __syncthreads();

    for (int st = 16; st > 0; st >>= 1) {
        if (jsub < st) {
#pragma unroll
            for (int dd = 0; dd < 16; ++dd)
                accH[jsub * 128 + dg * 16 + dd] += accH[(jsub + st) * 128 + dg * 16 + dd];
#pragma unroll
            for (int ff = 0; ff < 8; ++ff)
                accI[jsub * 64 + dg * 8 + ff] += accI[(jsub + st) * 64 + dg * 8 + ff];
            if (dg == 0) accS[jsub] += accS[jsub + st];
        }
        __syncthreads();
    }

    if (tid < F_) {
        int f = tid;
        float s = accS[0];
        float xv = 0.f;
#pragma unroll
        for (int d = 0; d < H_; ++d) xv = fmaf(accH[d], vW2[d * F_ + f], xv);
        float r = 0.5f * (xv + s * vb2[f]) +
                  0.25f * (s * inp[(size_t)(b * N_ + i) * F_ + f] + accI[f]);
        xout[(size_t)(b * N_ + i) * F_ + f] = r;
    }
}

// -------------------- launch --------------------

extern "C" void kernel_launch(void* const* d_in, const int* in_sizes, int n_in,
                              void* d_out, int out_size, void* d_ws, size_t ws_size,
                              hipStream_t stream) {
    const float* inp   = (const float*)d_in[0];
    const float* pos   = (const float*)d_in[1];
    const float* vW1   = (const float*)d_in[2];
    const float* vb1   = (const float*)d_in[3];
    const float* vg    = (const float*)d_in[4];
    const float* vbeta = (const float*)d_in[5];
    const float* vW2   = (const float*)d_in[6];
    const float* vb2   = (const float*)d_in[7];
    const float* sW1   = (const float*)d_in[8];
    const float* sb1   = (const float*)d_in[9];
    const float* sW2   = (const float*)d_in[10];
    const float* sb2   = (const float*)d_in[11];

    float* xout   = (float*)d_out;                 // B*N*F
    float* attout = xout + B_ * N_ * F_;           // B*N*N (scores -> att in place)

    unsigned short* W2hT = (unsigned short*)d_ws;          // 128*128 fp16 (32KB)
    float* t    = (float*)((char*)d_ws + 32768);           // B*N*128 fp32
    float* pmax = t + B_ * N_ * H_;                        // B*72
    float* psum = pmax + B_ * NCHUNK;                      // B*72

    k_prep_w2p<<<64, 256, 0, stream>>>(vW2, sW1, W2hT);
    k_prep_t<<<B_ * N_, 128, 0, stream>>>(inp, sW1, vb2, sb1, t);
    k_scores<<<dim3(96, B_), 256, 0, stream>>>(
        pos, vW1, vb1, vg, vbeta, W2hT, t, sW2, sb2, attout);
    k_pmax<<<dim3(NCHUNK, B_), 256, 0, stream>>>(attout, pmax);
    k_psum<<<dim3(NCHUNK, B_), 256, 0, stream>>>(attout, pmax, psum);
    k_att<<<dim3(N_, B_), 384, 0, stream>>>(attout, pmax, psum);
    k_x<<<dim3(N_, B_), 256, 0, stream>>>(inp, pos, vW1, vb1, vg, vbeta, vW2, vb2,
                                          attout, xout);
}

// Round 7
// 337.045 us; speedup vs baseline: 2.8415x; 2.5837x over previous
//
#include <hip/hip_runtime.h>
#include <hip/hip_bf16.h>
#include <math.h>

#define B_ 8
#define N_ 384
#define F_ 64
#define H_ 128
#define LN_EPS 1e-5f
#define NCHUNK 72          // N_*N_ / 2048

typedef _Float16 f16;
typedef f16 f16x8 __attribute__((ext_vector_type(8)));
typedef float f32x4v __attribute__((ext_vector_type(4)));

// -------------------- setup kernels --------------------

// W2hT[n][k] = fp16( 0.5 * sum_f vW2[k,f] * sW1[f,n] )   (128x128, TRANSPOSED for MFMA A)
__global__ void k_prep_w2p(const float* __restrict__ vW2, const float* __restrict__ sW1,
                           unsigned short* __restrict__ W2hT) {
    int idx = blockIdx.x * 256 + threadIdx.x;   // 0..16383
    int k = idx >> 7, n = idx & 127;
    float acc = 0.f;
#pragma unroll
    for (int f = 0; f < F_; ++f) acc = fmaf(vW2[k * F_ + f], sW1[f * H_ + n], acc);
    f16 hv = (f16)(0.5f * acc);
    W2hT[n * H_ + k] = *reinterpret_cast<unsigned short*>(&hv);
}

// t[row][n] = sum_f (0.25*(in[row,f]+vb2[f])) * sW1[f,n] + 0.5*sb1[n]
__global__ void k_prep_t(const float* __restrict__ inp, const float* __restrict__ sW1,
                         const float* __restrict__ vb2, const float* __restrict__ sb1,
                         float* __restrict__ t) {
    int row = blockIdx.x;
    int n = threadIdx.x;
    float acc = 0.f;
#pragma unroll
    for (int f = 0; f < F_; ++f)
        acc = fmaf(0.25f * (inp[row * F_ + f] + vb2[f]), sW1[f * H_ + n], acc);
    t[row * H_ + n] = acc + 0.5f * sb1[n];
}

// -------------------- phase 1: scores (persistent 4-wave blocks, LDS A-frags) --------------------
// Block = 256 threads = 4 waves. Stage W' (32KB fp16, swizzled) to LDS ONCE (+1 barrier).
// Wave w owns i-row = blockIdx.x*4 + w; loops 24 j-tiles of 16 pairs, barrier-free,
// wave-private 4KB rht region. Per tile:
//   phase A: relu(LN(inv@vW1+vb1)) -> rht (fp16, swizzled)
//   acc init = ti + tj (MFMA C-operand carries affine part)
//   GEMM: 4 kc x (1 B-read + 8 A-reads ds_read_b128 + 8 MFMA)
//   phase C: relu, dot sW2, 2-shfl reduce -> score
// NOTE: __launch_bounds__(256) with NO min-waves arg — a second arg of 3 capped VGPRs
// at ~85 and forced catastrophic scratch spills (R5/R6: 147-280MB WRITE_SIZE).
#define RHT_OFF 32768
__global__ __launch_bounds__(256) void k_scores(
    const float* __restrict__ pos, const float* __restrict__ vW1,
    const float* __restrict__ vb1, const float* __restrict__ vg,
    const float* __restrict__ vbeta, const unsigned short* __restrict__ W2hT,
    const float* __restrict__ t, const float* __restrict__ sW2,
    const float* __restrict__ sb2, float* __restrict__ scores) {
    __shared__ __align__(16) char smem[49152];   // 32KB W' + 4 x 4KB rht

    const int tid = threadIdx.x;
    const int b = blockIdx.y;
    const int w = tid >> 6;
    const int lane = tid & 63;
    const int i = blockIdx.x * 4 + w;

    // ---- stage W' once (all 256 threads), swizzled ----
#pragma unroll
    for (int s = 0; s < 8; ++s) {
        int idx = tid + s * 256;                 // 0..2047 16B chunks
        int n = idx >> 4, c = idx & 15;
        uint4 v = *(const uint4*)(W2hT + n * H_ + c * 8);
        *(uint4*)(smem + ((n * 256 + c * 16) ^ ((n & 7) << 4))) = v;
    }
    __syncthreads();

    char* rht = smem + RHT_OFF + w * 4096;

    const int ln = lane & 15, h4 = lane >> 4;    // MFMA lane coords
    const int ksw = (ln & 7) << 4;

    // per-wave fixed data
    const float* pi = pos + (size_t)(b * N_ + i) * 3;
    const float ax = pi[0], ay = pi[1], az = pi[2];

    float4 tiv[8], sw2r[8];
#pragma unroll
    for (int mf = 0; mf < 8; ++mf) {
        tiv[mf]  = *(const float4*)(t + (size_t)(b * N_ + i) * H_ + mf * 16 + h4 * 4);
        sw2r[mf] = *(const float4*)(sW2 + mf * 16 + h4 * 4);
    }
    const float sb2v = sb2[0];

    // phase-A lane roles: pair pA = lane>>2 (j = j0+pA), dim group lA = lane&3
    const int pA = lane >> 2, lA = lane & 3;
    const int d0 = lA * 32;
    const int wbA = pA * 256;
    const int pswA = (pA & 7) << 4;

    float* scoreRow = scores + (size_t)(b * N_ + i) * N_;

    for (int jt = 0; jt < 24; ++jt) {
        const int j0 = jt * 16;

        // ---- Phase A: 4 lanes per pair, 32 dims each -> rht fp16 ----
        {
            const float* pj = pos + (size_t)(b * N_ + j0 + pA) * 3;
            float bx = pj[0], by = pj[1], bz = pj[2];
            float dotv = ax * bx + ay * by + az * bz;
            float cx = ay * bz - az * by;
            float cy = az * bx - ax * bz;
            float cz = ax * by - ay * bx;
            float cn = sqrtf(cx * cx + cy * cy + cz * cz);

            float h[32];
            float s1 = 0.f, s2 = 0.f;
#pragma unroll
            for (int s = 0; s < 8; ++s) {
                float4 wa = *(const float4*)(vW1 + d0 + s * 4);
                float4 wb = *(const float4*)(vW1 + H_ + d0 + s * 4);
                float4 bv = *(const float4*)(vb1 + d0 + s * 4);
                float v;
                v = fmaf(dotv, wa.x, fmaf(cn, wb.x, bv.x)); h[s*4+0] = v; s1 += v; s2 = fmaf(v, v, s2);
                v = fmaf(dotv, wa.y, fmaf(cn, wb.y, bv.y)); h[s*4+1] = v; s1 += v; s2 = fmaf(v, v, s2);
                v = fmaf(dotv, wa.z, fmaf(cn, wb.z, bv.z)); h[s*4+2] = v; s1 += v; s2 = fmaf(v, v, s2);
                v = fmaf(dotv, wa.w, fmaf(cn, wb.w, bv.w)); h[s*4+3] = v; s1 += v; s2 = fmaf(v, v, s2);
            }
            s1 += __shfl_xor(s1, 1); s1 += __shfl_xor(s1, 2);
            s2 += __shfl_xor(s2, 1); s2 += __shfl_xor(s2, 2);
            float mu = s1 * (1.f / 128.f);
            float var = s2 * (1.f / 128.f) - mu * mu;
            float rstd = rsqrtf(var + LN_EPS);
#pragma unroll
            for (int s = 0; s < 4; ++s) {
                float4 g0 = *(const float4*)(vg + d0 + s * 8);
                float4 g1 = *(const float4*)(vg + d0 + s * 8 + 4);
                float4 e0 = *(const float4*)(vbeta + d0 + s * 8);
                float4 e1 = *(const float4*)(vbeta + d0 + s * 8 + 4);
                f16x8 pk;
                pk[0] = (f16)fmaxf(fmaf((h[s*8+0] - mu) * rstd, g0.x, e0.x), 0.f);
                pk[1] = (f16)fmaxf(fmaf((h[s*8+1] - mu) * rstd, g0.y, e0.y), 0.f);
                pk[2] = (f16)fmaxf(fmaf((h[s*8+2] - mu) * rstd, g0.z, e0.z), 0.f);
                pk[3] = (f16)fmaxf(fmaf((h[s*8+3] - mu) * rstd, g0.w, e0.w), 0.f);
                pk[4] = (f16)fmaxf(fmaf((h[s*8+4] - mu) * rstd, g1.x, e1.x), 0.f);
                pk[5] = (f16)fmaxf(fmaf((h[s*8+5] - mu) * rstd, g1.y, e1.y), 0.f);
                pk[6] = (f16)fmaxf(fmaf((h[s*8+6] - mu) * rstd, g1.z, e1.z), 0.f);
                pk[7] = (f16)fmaxf(fmaf((h[s*8+7] - mu) * rstd, g1.w, e1.w), 0.f);
                *(f16x8*)(rht + wbA + ((lA * 64 + s * 16) ^ pswA)) = pk;
            }
        }

        // ---- acc init = ti + tj ----
        f32x4v acc[8];
        const float* tjB = t + (size_t)(b * N_ + j0 + ln) * H_ + h4 * 4;
#pragma unroll
        for (int mf = 0; mf < 8; ++mf) {
            float4 tj = *(const float4*)(tjB + mf * 16);
            acc[mf][0] = tiv[mf].x + tj.x;
            acc[mf][1] = tiv[mf].y + tj.y;
            acc[mf][2] = tiv[mf].z + tj.z;
            acc[mf][3] = tiv[mf].w + tj.w;
        }

        // ---- GEMM: A (W') and B (rht) from LDS ----
#pragma unroll
        for (int kc = 0; kc < 4; ++kc) {
            const int kb = (kc * 64 + h4 * 16) ^ ksw;
            f16x8 bF = *(const f16x8*)(rht + ln * 256 + kb);
#pragma unroll
            for (int mf = 0; mf < 8; ++mf) {
                f16x8 aF = *(const f16x8*)(smem + (mf * 16 + ln) * 256 + kb);
                acc[mf] = __builtin_amdgcn_mfma_f32_16x16x32_f16(aF, bF, acc[mf], 0, 0, 0);
            }
        }

        // ---- Phase C: relu, dot sW2, reduce over h4 groups ----
        float part = 0.f;
#pragma unroll
        for (int mf = 0; mf < 8; ++mf) {
            part += fmaxf(acc[mf][0], 0.f) * sw2r[mf].x;
            part += fmaxf(acc[mf][1], 0.f) * sw2r[mf].y;
            part += fmaxf(acc[mf][2], 0.f) * sw2r[mf].z;
            part += fmaxf(acc[mf][3], 0.f) * sw2r[mf].w;
        }
        part += __shfl_xor(part, 16);
        part += __shfl_xor(part, 32);
        if (h4 == 0) scoreRow[j0 + ln] = part + sb2v;
    }
}

// -------------------- softmax reductions (deterministic trees) --------------------

__global__ void k_pmax(const float* __restrict__ scores, float* __restrict__ pmax) {
    int c = blockIdx.x, b = blockIdx.y;
    int tid = threadIdx.x;
    size_t base = (size_t)b * N_ * N_ + (size_t)c * 2048;
    float m = -1e30f;
#pragma unroll
    for (int s = 0; s < 8; ++s) m = fmaxf(m, scores[base + s * 256 + tid]);
    __shared__ float red[256];
    red[tid] = m;
    __syncthreads();
    for (int st = 128; st > 0; st >>= 1) {
        if (tid < st) red[tid] = fmaxf(red[tid], red[tid + st]);
        __syncthreads();
    }
    if (tid == 0) pmax[b * NCHUNK + c] = red[0];
}

__global__ void k_psum(const float* __restrict__ scores, const float* __restrict__ pmax,
                       float* __restrict__ psum) {
    int c = blockIdx.x, b = blockIdx.y;
    int tid = threadIdx.x;
    __shared__ float gm;
    __shared__ float red[256];
    if (tid == 0) {
        float m = -1e30f;
        for (int k = 0; k < NCHUNK; ++k) m = fmaxf(m, pmax[b * NCHUNK + k]);
        gm = m;
    }
    __syncthreads();
    size_t base = (size_t)b * N_ * N_ + (size_t)c * 2048;
    float s = 0.f;
#pragma unroll
    for (int k = 0; k < 8; ++k) s += expf(scores[base + k * 256 + tid] - gm);
    red[tid] = s;
    __syncthreads();
    for (int st = 128; st > 0; st >>= 1) {
        if (tid < st) red[tid] += red[tid + st];
        __syncthreads();
    }
    if (tid == 0) psum[b * NCHUNK + c] = red[0];
}

// normalize scores -> att in place (one block per (b,i) row)
__global__ void k_att(float* __restrict__ scores, const float* __restrict__ pmax,
                      const float* __restrict__ psum) {
    int i = blockIdx.x, b = blockIdx.y;
    int tid = threadIdx.x;   // 384
    __shared__ float gm, gs;
    if (tid == 0) {
        float m = -1e30f;
        for (int k = 0; k < NCHUNK; ++k) m = fmaxf(m, pmax[b * NCHUNK + k]);
        gm = m;
    } else if (tid == 1) {
        float s = 0.f;
        for (int k = 0; k < NCHUNK; ++k) s += psum[b * NCHUNK + k];
        gs = s;
    }
    __syncthreads();
    size_t idx = (size_t)(b * N_ + i) * N_ + tid;
    scores[idx] = expf(scores[idx] - gm) / gs;
}

// -------------------- phase 2: x --------------------
// One block per (b,i). Recompute relu_h fp32; accH = sum att*relu_h, accI = sum att*in_j,
// s = sum att. x = 0.5*(accH@vW2 + s*vb2) + 0.25*(s*in_i + accI)
__global__ __launch_bounds__(256) void k_x(
    const float* __restrict__ inp, const float* __restrict__ pos,
    const float* __restrict__ vW1, const float* __restrict__ vb1,
    const float* __restrict__ vg, const float* __restrict__ vbeta,
    const float* __restrict__ vW2, const float* __restrict__ vb2,
    const float* __restrict__ att, float* __restrict__ xout) {
    int i = blockIdx.x, b = blockIdx.y;
    int tid = threadIdx.x;
    int jsub = tid >> 3, dg = tid & 7;

    __shared__ float accH[32 * 128];
    __shared__ float accI[32 * 64];
    __shared__ float accS[32];

    float aH[16];
    float aI[8];
#pragma unroll
    for (int dd = 0; dd < 16; ++dd) aH[dd] = 0.f;
#pragma unroll
    for (int ff = 0; ff < 8; ++ff) aI[ff] = 0.f;
    float aS = 0.f;

    const float* pi = pos + (size_t)(b * N_ + i) * 3;
    float ax = pi[0], ay = pi[1], az = pi[2];

    for (int jc = 0; jc < 12; ++jc) {
        int j = jc * 32 + jsub;
        const float* pj = pos + (size_t)(b * N_ + j) * 3;
        float bx = pj[0], by = pj[1], bz = pj[2];
        float dotv = ax * bx + ay * by + az * bz;
        float cx = ay * bz - az * by;
        float cy = az * bx - ax * bz;
        float cz = ax * by - ay * bx;
        float cn = sqrtf(cx * cx + cy * cy + cz * cz);
        float a = att[(size_t)(b * N_ + i) * N_ + j];

        float h[16];
        float s1 = 0.f, s2 = 0.f;
#pragma unroll
        for (int dd = 0; dd < 16; ++dd) {
            int d = dg * 16 + dd;
            float v = fmaf(dotv, vW1[d], fmaf(cn, vW1[H_ + d], vb1[d]));
            h[dd] = v;
            s1 += v;
            s2 = fmaf(v, v, s2);
        }
        s1 += __shfl_xor(s1, 1); s1 += __shfl_xor(s1, 2); s1 += __shfl_xor(s1, 4);
        s2 += __shfl_xor(s2, 1); s2 += __shfl_xor(s2, 2); s2 += __shfl_xor(s2, 4);
        float mu = s1 * (1.f / 128.f);
        float var = s2 * (1.f / 128.f) - mu * mu;
        float rstd = rsqrtf(var + LN_EPS);
#pragma unroll
        for (int dd = 0; dd < 16; ++dd) {
            int d = dg * 16 + dd;
            float v = fmaf((h[dd] - mu) * rstd, vg[d], vbeta[d]);
            aH[dd] = fmaf(a, fmaxf(v, 0.f), aH[dd]);
        }
#pragma unroll
        for (int ff = 0; ff < 8; ++ff) {
            int f = dg * 8 + ff;
            aI[ff] = fmaf(a, inp[(size_t)(b * N_ + j) * F_ + f], aI[ff]);
        }
        if (dg == 0) aS += a;
    }

#pragma unroll
    for (int dd = 0; dd < 16; ++dd) accH[jsub * 128 + dg * 16 + dd] = aH[dd];
#pragma unroll
    for (int ff = 0; ff < 8; ++ff) accI[jsub * 64 + dg * 8 + ff] = aI[ff];
    if (dg == 0) accS[jsub] = aS;
    __syncthreads();

    for (int st = 16; st > 0; st >>= 1) {
        if (jsub < st) {
#pragma unroll
            for (int dd = 0; dd < 16; ++dd)
                accH[jsub * 128 + dg * 16 + dd] += accH[(jsub + st) * 128 + dg * 16 + dd];
#pragma unroll
            for (int ff = 0; ff < 8; ++ff)
                accI[jsub * 64 + dg * 8 + ff] += accI[(jsub + st) * 64 + dg * 8 + ff];
            if (dg == 0) accS[jsub] += accS[jsub + st];
        }
        __syncthreads();
    }

    if (tid < F_) {
        int f = tid;
        float s = accS[0];
        float xv = 0.f;
#pragma unroll
        for (int d = 0; d < H_; ++d) xv = fmaf(accH[d], vW2[d * F_ + f], xv);
        float r = 0.5f * (xv + s * vb2[f]) +
                  0.25f * (s * inp[(size_t)(b * N_ + i) * F_ + f] + accI[f]);
        xout[(size_t)(b * N_ + i) * F_ + f] = r;
    }
}

// -------------------- launch --------------------

extern "C" void kernel_launch(void* const* d_in, const int* in_sizes, int n_in,
                              void* d_out, int out_size, void* d_ws, size_t ws_size,
                              hipStream_t stream) {
    const float* inp   = (const float*)d_in[0];
    const float* pos   = (const float*)d_in[1];
    const float* vW1   = (const float*)d_in[2];
    const float* vb1   = (const float*)d_in[3];
    const float* vg    = (const float*)d_in[4];
    const float* vbeta = (const float*)d_in[5];
    const float* vW2   = (const float*)d_in[6];
    const float* vb2   = (const float*)d_in[7];
    const float* sW1   = (const float*)d_in[8];
    const float* sb1   = (const float*)d_in[9];
    const float* sW2   = (const float*)d_in[10];
    const float* sb2   = (const float*)d_in[11];

    float* xout   = (float*)d_out;                 // B*N*F
    float* attout = xout + B_ * N_ * F_;           // B*N*N (scores -> att in place)

    unsigned short* W2hT = (unsigned short*)d_ws;          // 128*128 fp16 (32KB)
    float* t    = (float*)((char*)d_ws + 32768);           // B*N*128 fp32
    float* pmax = t + B_ * N_ * H_;                        // B*72
    float* psum = pmax + B_ * NCHUNK;                      // B*72

    k_prep_w2p<<<64, 256, 0, stream>>>(vW2, sW1, W2hT);
    k_prep_t<<<B_ * N_, 128, 0, stream>>>(inp, sW1, vb2, sb1, t);
    k_scores<<<dim3(96, B_), 256, 0, stream>>>(
        pos, vW1, vb1, vg, vbeta, W2hT, t, sW2, sb2, attout);
    k_pmax<<<dim3(NCHUNK, B_), 256, 0, stream>>>(attout, pmax);
    k_psum<<<dim3(NCHUNK, B_), 256, 0, stream>>>(attout, pmax, psum);
    k_att<<<dim3(N_, B_), 384, 0, stream>>>(attout, pmax, psum);
    k_x<<<dim3(N_, B_), 256, 0, stream>>>(inp, pos, vW1, vb1, vg, vbeta, vW2, vb2,
                                          attout, xout);
}

// Round 8
// 242.822 us; speedup vs baseline: 3.9441x; 1.3880x over previous
//
#include <hip/hip_runtime.h>
#include <hip/hip_bf16.h>
#include <math.h>

#define B_ 8
#define N_ 384
#define F_ 64
#define H_ 128
#define LN_EPS 1e-5f
#define NCHUNK 72          // N_*N_ / 2048

typedef _Float16 f16;
typedef f16 f16x2 __attribute__((ext_vector_type(2)));
typedef f16 f16x4 __attribute__((ext_vector_type(4)));
typedef f16 f16x8 __attribute__((ext_vector_type(8)));
typedef float f32x4v __attribute__((ext_vector_type(4)));

static __device__ __forceinline__ f16x2 u2h(unsigned int u) {
    union { unsigned int u; f16x2 h; } c; c.u = u; return c.h;
}

// -------------------- setup kernels --------------------

// W2hT[n][k] = fp16( 0.5 * sum_f vW2[k,f] * sW1[f,n] )   (128x128, TRANSPOSED for MFMA A)
__global__ void k_prep_w2p(const float* __restrict__ vW2, const float* __restrict__ sW1,
                           unsigned short* __restrict__ W2hT) {
    int idx = blockIdx.x * 256 + threadIdx.x;   // 0..16383
    int k = idx >> 7, n = idx & 127;
    float acc = 0.f;
#pragma unroll
    for (int f = 0; f < F_; ++f) acc = fmaf(vW2[k * F_ + f], sW1[f * H_ + n], acc);
    f16 hv = (f16)(0.5f * acc);
    W2hT[n * H_ + k] = *reinterpret_cast<unsigned short*>(&hv);
}

// t[row][n] = sum_f (0.25*(in[row,f]+vb2[f])) * sW1[f,n] + 0.5*sb1[n]
__global__ void k_prep_t(const float* __restrict__ inp, const float* __restrict__ sW1,
                         const float* __restrict__ vb2, const float* __restrict__ sb1,
                         float* __restrict__ t) {
    int row = blockIdx.x;
    int n = threadIdx.x;
    float acc = 0.f;
#pragma unroll
    for (int f = 0; f < F_; ++f)
        acc = fmaf(0.25f * (inp[row * F_ + f] + vb2[f]), sW1[f * H_ + n], acc);
    t[row * H_ + n] = acc + 0.5f * sb1[n];
}

// Algebraic-LN coefficients: centered ca/cb/cc (·vg, fp16-packed) + 6 covariance scalars.
// h[d] = dot*W1a[d]+cn*W1b[d]+b[d];  mu = dot*mA+cn*mB+mC (linear)
// var  = Saa dot^2 + Sbb cn^2 + Scc + 2(Sab dot cn + Sac dot + Sbc cn)
// ln[d]= (h-mu)*rstd*vg+vbeta = dot*rstd*cag + cn*rstd*cbg + rstd*ccg + vbeta
__global__ void k_prep_coeff(const float* __restrict__ vW1, const float* __restrict__ vb1,
                             const float* __restrict__ vg, const float* __restrict__ vbeta,
                             unsigned int* __restrict__ coeffP, float* __restrict__ scal) {
    __shared__ float red[128];
    __shared__ float caS[128], cbS[128], ccS[128];
    const int d = threadIdx.x;   // 128
    float a = vW1[d], bb = vW1[H_ + d], c = vb1[d];

    float mA, mB, mC, Saa, Sbb, Scc, Sab, Sac, Sbc;
    float ca, cb, cc;
#define BMEAN(OUT, VAL)                                                  \
    red[d] = (VAL); __syncthreads();                                     \
    for (int st = 64; st > 0; st >>= 1) {                                \
        if (d < st) red[d] += red[d + st];                               \
        __syncthreads();                                                 \
    }                                                                    \
    OUT = red[0] * (1.f / 128.f); __syncthreads();

    BMEAN(mA, a); BMEAN(mB, bb); BMEAN(mC, c);
    ca = a - mA; cb = bb - mB; cc = c - mC;
    caS[d] = ca * vg[d]; cbS[d] = cb * vg[d]; ccS[d] = cc * vg[d];
    BMEAN(Saa, ca * ca); BMEAN(Sbb, cb * cb); BMEAN(Scc, cc * cc);
    BMEAN(Sab, ca * cb); BMEAN(Sac, ca * cc); BMEAN(Sbc, cb * cc);
#undef BMEAN
    __syncthreads();
    if (d < 64) {
        int d0 = 2 * d;
        union { f16x2 h; unsigned int u; } cv;
        cv.h = (f16x2){(f16)caS[d0], (f16)caS[d0 + 1]};   coeffP[d]       = cv.u;
        cv.h = (f16x2){(f16)cbS[d0], (f16)cbS[d0 + 1]};   coeffP[64 + d]  = cv.u;
        cv.h = (f16x2){(f16)ccS[d0], (f16)ccS[d0 + 1]};   coeffP[128 + d] = cv.u;
        cv.h = (f16x2){(f16)vbeta[d0], (f16)vbeta[d0 + 1]}; coeffP[192 + d] = cv.u;
    }
    if (d == 0) {
        scal[0] = Saa; scal[1] = Sbb; scal[2] = Scc;
        scal[3] = Sab; scal[4] = Sac; scal[5] = Sbc;
    }
}

// -------------------- phase 1: scores --------------------
// Block = 4 waves; wave w owns i-row blockIdx.x*4+w; 24 j-tiles of 16 pairs; barrier-free.
// W' A-frags RESIDENT in 128 VGPRs. Phase A = algebraic LN in packed f16 (no reductions).
// ti/sW2 in wave-private LDS. LDS/tile = 4 writes + 4 B-reads + 8 ti + 8 sW2.
// __launch_bounds__(256) only — min-waves arg caps VGPR at 256/arg => spills (R5/R6).
#define LDS_TI  16384
#define LDS_SW  18432
__global__ __launch_bounds__(256) void k_scores(
    const float* __restrict__ pos, const unsigned int* __restrict__ coeffP,
    const float* __restrict__ scal, const unsigned short* __restrict__ W2hT,
    const float* __restrict__ t, const float* __restrict__ sW2,
    const float* __restrict__ sb2, float* __restrict__ scores) {
    __shared__ __align__(16) char smem[20480];   // 4x4KB rht + 4x512B ti + 4x512B sW2

    const int tid = threadIdx.x;
    const int b = blockIdx.y;
    const int w = tid >> 6, lane = tid & 63;
    const int i = blockIdx.x * 4 + w;
    const int ln = lane & 15, h4 = lane >> 4;

    char* rht = smem + w * 4096;
    char* tiS = smem + LDS_TI + w * 512;
    char* swS = smem + LDS_SW + w * 512;

    // stage wave-private ti and sW2 copies (same-wave ordering, no barrier)
    if (lane < 32) {
        *(float4*)(tiS + lane * 16) = *(const float4*)(t + (size_t)(b * N_ + i) * H_ + lane * 4);
        *(float4*)(swS + lane * 16) = *(const float4*)(sW2 + lane * 4);
    }

    // A-fragments resident (128 VGPR)
    f16x8 aF[8][4];
#pragma unroll
    for (int mf = 0; mf < 8; ++mf)
#pragma unroll
        for (int kc = 0; kc < 4; ++kc)
            aF[mf][kc] = *(const f16x8*)(W2hT + (mf * 16 + ln) * H_ + kc * 32 + h4 * 8);

    // this lane's 16 phase-A dims: lA = lane&7 -> dims lA*16.. -> packed pairs lA*8..+7
    const int lA = lane & 7;
    const uint4 cagA = *(const uint4*)(coeffP + lA * 8);
    const uint4 cagB = *(const uint4*)(coeffP + lA * 8 + 4);
    const uint4 cbgA = *(const uint4*)(coeffP + 64 + lA * 8);
    const uint4 cbgB = *(const uint4*)(coeffP + 64 + lA * 8 + 4);
    const uint4 ccgA = *(const uint4*)(coeffP + 128 + lA * 8);
    const uint4 ccgB = *(const uint4*)(coeffP + 128 + lA * 8 + 4);
    const uint4 vbA  = *(const uint4*)(coeffP + 192 + lA * 8);
    const uint4 vbB  = *(const uint4*)(coeffP + 192 + lA * 8 + 4);

    const float Saa = scal[0], Sbb = scal[1], Scc = scal[2];
    const float Sab = scal[3], Sac = scal[4], Sbc = scal[5];
    const float sb2v = sb2[0];

    const float* pi = pos + (size_t)(b * N_ + i) * 3;
    const float ax = pi[0], ay = pi[1], az = pi[2];
    const int pA8 = lane >> 3;   // phase-A pair-within-pass

    float* scoreRow = scores + (size_t)(b * N_ + i) * N_;

#pragma unroll 1
    for (int jt = 0; jt < 24; ++jt) {
        const int j0 = jt * 16;

        // ---- Phase A: 2 passes x 8 pairs; 8 lanes/pair x 16 dims, packed f16 ----
#pragma unroll
        for (int q = 0; q < 2; ++q) {
            const int pq = q * 8 + pA8;
            const float* pj = pos + (size_t)(b * N_ + j0 + pq) * 3;
            float bx = pj[0], by = pj[1], bz = pj[2];
            float dotv = ax * bx + ay * by + az * bz;
            float cx = ay * bz - az * by;
            float cy = az * bx - ax * bz;
            float cz = ax * by - ay * bx;
            float cns = cx * cx + cy * cy + cz * cz;
            float cn = sqrtf(cns);
            float var = Saa * dotv * dotv + Sbb * cns + Scc +
                        2.f * (Sab * dotv * cn + Sac * dotv + Sbc * cn);
            float rstd = rsqrtf(var + LN_EPS);
            f16 d2 = (f16)(dotv * rstd), c2 = (f16)(cn * rstd), r2 = (f16)rstd;
            f16x2 D2 = {d2, d2}, C2 = {c2, c2}, R2 = {r2, r2};
            const f16x2 Z = {(f16)0.f, (f16)0.f};

            f16x2 vp0 = __builtin_elementwise_max(D2 * u2h(cagA.x) + (C2 * u2h(cbgA.x) + (R2 * u2h(ccgA.x) + u2h(vbA.x))), Z);
            f16x2 vp1 = __builtin_elementwise_max(D2 * u2h(cagA.y) + (C2 * u2h(cbgA.y) + (R2 * u2h(ccgA.y) + u2h(vbA.y))), Z);
            f16x2 vp2 = __builtin_elementwise_max(D2 * u2h(cagA.z) + (C2 * u2h(cbgA.z) + (R2 * u2h(ccgA.z) + u2h(vbA.z))), Z);
            f16x2 vp3 = __builtin_elementwise_max(D2 * u2h(cagA.w) + (C2 * u2h(cbgA.w) + (R2 * u2h(ccgA.w) + u2h(vbA.w))), Z);
            f16x2 vp4 = __builtin_elementwise_max(D2 * u2h(cagB.x) + (C2 * u2h(cbgB.x) + (R2 * u2h(ccgB.x) + u2h(vbB.x))), Z);
            f16x2 vp5 = __builtin_elementwise_max(D2 * u2h(cagB.y) + (C2 * u2h(cbgB.y) + (R2 * u2h(ccgB.y) + u2h(vbB.y))), Z);
            f16x2 vp6 = __builtin_elementwise_max(D2 * u2h(cagB.z) + (C2 * u2h(cbgB.z) + (R2 * u2h(ccgB.z) + u2h(vbB.z))), Z);
            f16x2 vp7 = __builtin_elementwise_max(D2 * u2h(cagB.w) + (C2 * u2h(cbgB.w) + (R2 * u2h(ccgB.w) + u2h(vbB.w))), Z);

            f16x4 q0 = __builtin_shufflevector(vp0, vp1, 0, 1, 2, 3);
            f16x4 q1 = __builtin_shufflevector(vp2, vp3, 0, 1, 2, 3);
            f16x4 q2 = __builtin_shufflevector(vp4, vp5, 0, 1, 2, 3);
            f16x4 q3 = __builtin_shufflevector(vp6, vp7, 0, 1, 2, 3);
            f16x8 o0 = __builtin_shufflevector(q0, q1, 0, 1, 2, 3, 4, 5, 6, 7);
            f16x8 o1 = __builtin_shufflevector(q2, q3, 0, 1, 2, 3, 4, 5, 6, 7);

            const int rb = pq * 256, sw = (pq & 7) << 4;
            *(f16x8*)(rht + rb + ((lA * 32) ^ sw)) = o0;
            *(f16x8*)(rht + rb + ((lA * 32 + 16) ^ sw)) = o1;
        }

        // ---- acc init = ti + tj ----
        f32x4v acc[8];
        const float* tjB = t + (size_t)(b * N_ + j0 + ln) * H_ + h4 * 4;
#pragma unroll
        for (int mf = 0; mf < 8; ++mf) {
            float4 tiv = *(const float4*)(tiS + mf * 64 + h4 * 16);
            float4 tj = *(const float4*)(tjB + mf * 16);
            acc[mf][0] = tiv.x + tj.x;
            acc[mf][1] = tiv.y + tj.y;
            acc[mf][2] = tiv.z + tj.z;
            acc[mf][3] = tiv.w + tj.w;
        }

        // ---- GEMM: A in regs, B from wave-private rht ----
#pragma unroll
        for (int kc = 0; kc < 4; ++kc) {
            f16x8 bF = *(const f16x8*)(rht + ln * 256 + ((kc * 64 + h4 * 16) ^ ((ln & 7) << 4)));
#pragma unroll
            for (int mf = 0; mf < 8; ++mf)
                acc[mf] = __builtin_amdgcn_mfma_f32_16x16x32_f16(aF[mf][kc], bF, acc[mf], 0, 0, 0);
        }

        // ---- Phase C: relu, dot sW2, reduce over h4 ----
        float part = 0.f;
#pragma unroll
        for (int mf = 0; mf < 8; ++mf) {
            float4 swv = *(const float4*)(swS + mf * 64 + h4 * 16);
            part += fmaxf(acc[mf][0], 0.f) * swv.x;
            part += fmaxf(acc[mf][1], 0.f) * swv.y;
            part += fmaxf(acc[mf][2], 0.f) * swv.z;
            part += fmaxf(acc[mf][3], 0.f) * swv.w;
        }
        part += __shfl_xor(part, 16);
        part += __shfl_xor(part, 32);
        if (h4 == 0) scoreRow[j0 + ln] = part + sb2v;
    }
}

// -------------------- softmax reductions (deterministic trees) --------------------

__global__ void k_pmax(const float* __restrict__ scores, float* __restrict__ pmax) {
    int c = blockIdx.x, b = blockIdx.y;
    int tid = threadIdx.x;
    size_t base = (size_t)b * N_ * N_ + (size_t)c * 2048;
    float m = -1e30f;
#pragma unroll
    for (int s = 0; s < 8; ++s) m = fmaxf(m, scores[base + s * 256 + tid]);
    __shared__ float red[256];
    red[tid] = m;
    __syncthreads();
    for (int st = 128; st > 0; st >>= 1) {
        if (tid < st) red[tid] = fmaxf(red[tid], red[tid + st]);
        __syncthreads();
    }
    if (tid == 0) pmax[b * NCHUNK + c] = red[0];
}

__global__ void k_psum(const float* __restrict__ scores, const float* __restrict__ pmax,
                       float* __restrict__ psum) {
    int c = blockIdx.x, b = blockIdx.y;
    int tid = threadIdx.x;
    __shared__ float gm;
    __shared__ float red[256];
    if (tid == 0) {
        float m = -1e30f;
        for (int k = 0; k < NCHUNK; ++k) m = fmaxf(m, pmax[b * NCHUNK + k]);
        gm = m;
    }
    __syncthreads();
    size_t base = (size_t)b * N_ * N_ + (size_t)c * 2048;
    float s = 0.f;
#pragma unroll
    for (int k = 0; k < 8; ++k) s += expf(scores[base + k * 256 + tid] - gm);
    red[tid] = s;
    __syncthreads();
    for (int st = 128; st > 0; st >>= 1) {
        if (tid < st) red[tid] += red[tid + st];
        __syncthreads();
    }
    if (tid == 0) psum[b * NCHUNK + c] = red[0];
}

// normalize scores -> att in place (one block per (b,i) row)
__global__ void k_att(float* __restrict__ scores, const float* __restrict__ pmax,
                      const float* __restrict__ psum) {
    int i = blockIdx.x, b = blockIdx.y;
    int tid = threadIdx.x;   // 384
    __shared__ float gm, gs;
    if (tid == 0) {
        float m = -1e30f;
        for (int k = 0; k < NCHUNK; ++k) m = fmaxf(m, pmax[b * NCHUNK + k]);
        gm = m;
    } else if (tid == 1) {
        float s = 0.f;
        for (int k = 0; k < NCHUNK; ++k) s += psum[b * NCHUNK + k];
        gs = s;
    }
    __syncthreads();
    size_t idx = (size_t)(b * N_ + i) * N_ + tid;
    scores[idx] = expf(scores[idx] - gm) / gs;
}

// -------------------- phase 2: x --------------------
__global__ __launch_bounds__(256) void k_x(
    const float* __restrict__ inp, const float* __restrict__ pos,
    const float* __restrict__ vW1, const float* __restrict__ vb1,
    const float* __restrict__ vg, const float* __restrict__ vbeta,
    const float* __restrict__ vW2, const float* __restrict__ vb2,
    const float* __restrict__ att, float* __restrict__ xout) {
    int i = blockIdx.x, b = blockIdx.y;
    int tid = threadIdx.x;
    int jsub = tid >> 3, dg = tid & 7;

    __shared__ float accH[32 * 128];
    __shared__ float accI[32 * 64];
    __shared__ float accS[32];

    float aH[16];
    float aI[8];
#pragma unroll
    for (int dd = 0; dd < 16; ++dd) aH[dd] = 0.f;
#pragma unroll
    for (int ff = 0; ff < 8; ++ff) aI[ff] = 0.f;
    float aS = 0.f;

    const float* pi = pos + (size_t)(b * N_ + i) * 3;
    float ax = pi[0], ay = pi[1], az = pi[2];

    for (int jc = 0; jc < 12; ++jc) {
        int j = jc * 32 + jsub;
        const float* pj = pos + (size_t)(b * N_ + j) * 3;
        float bx = pj[0], by = pj[1], bz = pj[2];
        float dotv = ax * bx + ay * by + az * bz;
        float cx = ay * bz - az * by;
        float cy = az * bx - ax * bz;
        float cz = ax * by - ay * bx;
        float cn = sqrtf(cx * cx + cy * cy + cz * cz);
        float a = att[(size_t)(b * N_ + i) * N_ + j];

        float h[16];
        float s1 = 0.f, s2 = 0.f;
#pragma unroll
        for (int dd = 0; dd < 16; ++dd) {
            int d = dg * 16 + dd;
            float v = fmaf(dotv, vW1[d], fmaf(cn, vW1[H_ + d], vb1[d]));
            h[dd] = v;
            s1 += v;
            s2 = fmaf(v, v, s2);
        }
        s1 += __shfl_xor(s1, 1); s1 += __shfl_xor(s1, 2); s1 += __shfl_xor(s1, 4);
        s2 += __shfl_xor(s2, 1); s2 += __shfl_xor(s2, 2); s2 += __shfl_xor(s2, 4);
        float mu = s1 * (1.f / 128.f);
        float var = s2 * (1.f / 128.f) - mu * mu;
        float rstd = rsqrtf(var + LN_EPS);
#pragma unroll
        for (int dd = 0; dd < 16; ++dd) {
            int d = dg * 16 + dd;
            float v = fmaf((h[dd] - mu) * rstd, vg[d], vbeta[d]);
            aH[dd] = fmaf(a, fmaxf(v, 0.f), aH[dd]);
        }
#pragma unroll
        for (int ff = 0; ff < 8; ++ff) {
            int f = dg * 8 + ff;
            aI[ff] = fmaf(a, inp[(size_t)(b * N_ + j) * F_ + f], aI[ff]);
        }
        if (dg == 0) aS += a;
    }

#pragma unroll
    for (int dd = 0; dd < 16; ++dd) accH[jsub * 128 + dg * 16 + dd] = aH[dd];
#pragma unroll
    for (int ff = 0; ff < 8; ++ff) accI[jsub * 64 + dg * 8 + ff] = aI[ff];
    if (dg == 0) accS[jsub] = aS;
    __syncthreads();

    for (int st = 16; st > 0; st >>= 1) {
        if (jsub < st) {
#pragma unroll
            for (int dd = 0; dd < 16; ++dd)
                accH[jsub * 128 + dg * 16 + dd] += accH[(jsub + st) * 128 + dg * 16 + dd];
#pragma unroll
            for (int ff = 0; ff < 8; ++ff)
                accI[jsub * 64 + dg * 8 + ff] += accI[(jsub + st) * 64 + dg * 8 + ff];
            if (dg == 0) accS[jsub] += accS[jsub + st];
        }
        __syncthreads();
    }

    if (tid < F_) {
        int f = tid;
        float s = accS[0];
        float xv = 0.f;
#pragma unroll
        for (int d = 0; d < H_; ++d) xv = fmaf(accH[d], vW2[d * F_ + f], xv);
        float r = 0.5f * (xv + s * vb2[f]) +
                  0.25f * (s * inp[(size_t)(b * N_ + i) * F_ + f] + accI[f]);
        xout[(size_t)(b * N_ + i) * F_ + f] = r;
    }
}

// -------------------- launch --------------------

extern "C" void kernel_launch(void* const* d_in, const int* in_sizes, int n_in,
                              void* d_out, int out_size, void* d_ws, size_t ws_size,
                              hipStream_t stream) {
    const float* inp   = (const float*)d_in[0];
    const float* pos   = (const float*)d_in[1];
    const float* vW1   = (const float*)d_in[2];
    const float* vb1   = (const float*)d_in[3];
    const float* vg    = (const float*)d_in[4];
    const float* vbeta = (const float*)d_in[5];
    const float* vW2   = (const float*)d_in[6];
    const float* vb2   = (const float*)d_in[7];
    const float* sW1   = (const float*)d_in[8];
    const float* sb1   = (const float*)d_in[9];
    const float* sW2   = (const float*)d_in[10];
    const float* sb2   = (const float*)d_in[11];

    float* xout   = (float*)d_out;                 // B*N*F
    float* attout = xout + B_ * N_ * F_;           // B*N*N (scores -> att in place)

    unsigned short* W2hT  = (unsigned short*)d_ws;             // 32KB fp16
    unsigned int*   coeff = (unsigned int*)((char*)d_ws + 32768);   // 1KB packed f16x2
    float*          scal  = (float*)((char*)d_ws + 33792);     // 6 scalars
    float* t    = (float*)((char*)d_ws + 34816);               // B*N*128 fp32
    float* pmax = t + B_ * N_ * H_;                            // B*72
    float* psum = pmax + B_ * NCHUNK;                          // B*72

    k_prep_w2p<<<64, 256, 0, stream>>>(vW2, sW1, W2hT);
    k_prep_coeff<<<1, 128, 0, stream>>>(vW1, vb1, vg, vbeta, coeff, scal);
    k_prep_t<<<B_ * N_, 128, 0, stream>>>(inp, sW1, vb2, sb1, t);
    k_scores<<<dim3(96, B_), 256, 0, stream>>>(
        pos, coeff, scal, W2hT, t, sW2, sb2, attout);
    k_pmax<<<dim3(NCHUNK, B_), 256, 0, stream>>>(attout, pmax);
    k_psum<<<dim3(NCHUNK, B_), 256, 0, stream>>>(attout, pmax, psum);
    k_att<<<dim3(N_, B_), 384, 0, stream>>>(attout, pmax, psum);
    k_x<<<dim3(N_, B_), 256, 0, stream>>>(inp, pos, vW1, vb1, vg, vbeta, vW2, vb2,
                                          attout, xout);
}

// Round 9
// 218.706 us; speedup vs baseline: 4.3790x; 1.1103x over previous
//
#include <hip/hip_runtime.h>
#include <hip/hip_bf16.h>
#include <math.h>

#define B_ 8
#define N_ 384
#define F_ 64
#define H_ 128
#define LN_EPS 1e-5f
#define NCHUNK 72          // N_*N_ / 2048

typedef _Float16 f16;
typedef f16 f16x2 __attribute__((ext_vector_type(2)));
typedef f16 f16x4 __attribute__((ext_vector_type(4)));
typedef f16 f16x8 __attribute__((ext_vector_type(8)));
typedef float f32x4v __attribute__((ext_vector_type(4)));

static __device__ __forceinline__ f16x2 u2h(unsigned int u) {
    union { unsigned int u; f16x2 h; } c; c.u = u; return c.h;
}

// -------------------- setup kernels --------------------

// W2hT[n][k] = fp16( 0.5 * sum_f vW2[k,f] * sW1[f,n] )   (128x128, TRANSPOSED for MFMA A)
__global__ void k_prep_w2p(const float* __restrict__ vW2, const float* __restrict__ sW1,
                           unsigned short* __restrict__ W2hT) {
    int idx = blockIdx.x * 256 + threadIdx.x;   // 0..16383
    int k = idx >> 7, n = idx & 127;
    float acc = 0.f;
#pragma unroll
    for (int f = 0; f < F_; ++f) acc = fmaf(vW2[k * F_ + f], sW1[f * H_ + n], acc);
    f16 hv = (f16)(0.5f * acc);
    W2hT[n * H_ + k] = *reinterpret_cast<unsigned short*>(&hv);
}

// t[row][n] = sum_f (0.25*(in[row,f]+vb2[f])) * sW1[f,n] + 0.5*sb1[n]
__global__ void k_prep_t(const float* __restrict__ inp, const float* __restrict__ sW1,
                         const float* __restrict__ vb2, const float* __restrict__ sb1,
                         float* __restrict__ t) {
    int row = blockIdx.x;
    int n = threadIdx.x;
    float acc = 0.f;
#pragma unroll
    for (int f = 0; f < F_; ++f)
        acc = fmaf(0.25f * (inp[row * F_ + f] + vb2[f]), sW1[f * H_ + n], acc);
    t[row * H_ + n] = acc + 0.5f * sb1[n];
}

// Algebraic-LN coefficients: centered ca/cb/cc (·vg) as packed f16 (k_scores) and
// fp32 (k_x), + 6 covariance scalars.
__global__ void k_prep_coeff(const float* __restrict__ vW1, const float* __restrict__ vb1,
                             const float* __restrict__ vg, const float* __restrict__ vbeta,
                             unsigned int* __restrict__ coeffP, float* __restrict__ scal,
                             float* __restrict__ coeffF) {
    __shared__ float red[128];
    __shared__ float caS[128], cbS[128], ccS[128];
    const int d = threadIdx.x;   // 128
    float a = vW1[d], bb = vW1[H_ + d], c = vb1[d];

    float mA, mB, mC, Saa, Sbb, Scc, Sab, Sac, Sbc;
    float ca, cb, cc;
#define BMEAN(OUT, VAL)                                                  \
    red[d] = (VAL); __syncthreads();                                     \
    for (int st = 64; st > 0; st >>= 1) {                                \
        if (d < st) red[d] += red[d + st];                               \
        __syncthreads();                                                 \
    }                                                                    \
    OUT = red[0] * (1.f / 128.f); __syncthreads();

    BMEAN(mA, a); BMEAN(mB, bb); BMEAN(mC, c);
    ca = a - mA; cb = bb - mB; cc = c - mC;
    caS[d] = ca * vg[d]; cbS[d] = cb * vg[d]; ccS[d] = cc * vg[d];
    BMEAN(Saa, ca * ca); BMEAN(Sbb, cb * cb); BMEAN(Scc, cc * cc);
    BMEAN(Sab, ca * cb); BMEAN(Sac, ca * cc); BMEAN(Sbc, cb * cc);
#undef BMEAN
    __syncthreads();
    coeffF[d] = caS[d]; coeffF[128 + d] = cbS[d]; coeffF[256 + d] = ccS[d];
    if (d < 64) {
        int d0 = 2 * d;
        union { f16x2 h; unsigned int u; } cv;
        cv.h = (f16x2){(f16)caS[d0], (f16)caS[d0 + 1]};   coeffP[d]       = cv.u;
        cv.h = (f16x2){(f16)cbS[d0], (f16)cbS[d0 + 1]};   coeffP[64 + d]  = cv.u;
        cv.h = (f16x2){(f16)ccS[d0], (f16)ccS[d0 + 1]};   coeffP[128 + d] = cv.u;
        cv.h = (f16x2){(f16)vbeta[d0], (f16)vbeta[d0 + 1]}; coeffP[192 + d] = cv.u;
    }
    if (d == 0) {
        scal[0] = Saa; scal[1] = Sbb; scal[2] = Scc;
        scal[3] = Sab; scal[4] = Sac; scal[5] = Sbc;
    }
}

// -------------------- phase 1: scores (pipelined) --------------------
// Block = 4 waves; wave w owns i-row blockIdx.x*4+w; 24 j-tiles of 16 pairs, barrier-free.
// Cross-tile software pipeline: double-buffered rht; per iter: prefetch pos(t+1) +
// acc(t+1)=ti+tj(t+1) (VMEM off-chain) -> GEMM(t) -> phaseA(t+1) -> phaseC(t).
// A-frags of W' resident in 128 VGPR. ~245 VGPR planned (2 waves/SIMD), ILP carries.
// __launch_bounds__(256) only — min-waves arg caps VGPR at 256/arg => spills (R5/R6).
__global__ __launch_bounds__(256) void k_scores(
    const float* __restrict__ pos, const unsigned int* __restrict__ coeffP,
    const float* __restrict__ scal, const unsigned short* __restrict__ W2hT,
    const float* __restrict__ t, const float* __restrict__ sW2,
    const float* __restrict__ sb2, float* __restrict__ scores) {
    __shared__ __align__(16) char smem[36864];   // 4w x (4KB rht0 + 4KB rht1) + 4x512 ti + 4x512 sW2

    const int tid = threadIdx.x;
    const int b = blockIdx.y;
    const int w = tid >> 6, lane = tid & 63;
    const int i = blockIdx.x * 4 + w;
    const int ln = lane & 15, h4 = lane >> 4;

    char* rht0 = smem + w * 8192;
    char* rht1 = rht0 + 4096;
    char* tiS = smem + 32768 + w * 512;
    char* swS = smem + 34816 + w * 512;

    // stage wave-private ti and sW2 copies (same-wave ordering, no barrier)
    if (lane < 32) {
        *(float4*)(tiS + lane * 16) = *(const float4*)(t + (size_t)(b * N_ + i) * H_ + lane * 4);
        *(float4*)(swS + lane * 16) = *(const float4*)(sW2 + lane * 4);
    }

    // A-fragments resident (128 VGPR)
    f16x8 aF[8][4];
#pragma unroll
    for (int mf = 0; mf < 8; ++mf)
#pragma unroll
        for (int kc = 0; kc < 4; ++kc)
            aF[mf][kc] = *(const f16x8*)(W2hT + (mf * 16 + ln) * H_ + kc * 32 + h4 * 8);

    // phase-A per-lane coeffs: lA = lane&7 -> dims lA*16..+15 (packed f16x2)
    const int lA = lane & 7;
    const uint4 cagA = *(const uint4*)(coeffP + lA * 8);
    const uint4 cagB = *(const uint4*)(coeffP + lA * 8 + 4);
    const uint4 cbgA = *(const uint4*)(coeffP + 64 + lA * 8);
    const uint4 cbgB = *(const uint4*)(coeffP + 64 + lA * 8 + 4);
    const uint4 ccgA = *(const uint4*)(coeffP + 128 + lA * 8);
    const uint4 ccgB = *(const uint4*)(coeffP + 128 + lA * 8 + 4);
    const uint4 vbA  = *(const uint4*)(coeffP + 192 + lA * 8);
    const uint4 vbB  = *(const uint4*)(coeffP + 192 + lA * 8 + 4);

    const float Saa = scal[0], Sbb = scal[1], Scc = scal[2];
    const float Sab = scal[3], Sac = scal[4], Sbc = scal[5];
    const float sb2v = sb2[0];

    const float* pi = pos + (size_t)(b * N_ + i) * 3;
    const float ax = pi[0], ay = pi[1], az = pi[2];
    const int pA8 = lane >> 3;   // phase-A pair-within-pass

    float* scoreRow = scores + (size_t)(b * N_ + i) * N_;

    auto prefPos = [&](int jt, float& b0x, float& b0y, float& b0z,
                       float& b1x, float& b1y, float& b1z) {
        const float* pj0 = pos + (size_t)(b * N_ + jt * 16 + pA8) * 3;
        const float* pj1 = pj0 + 24;   // +8 rows * 3
        b0x = pj0[0]; b0y = pj0[1]; b0z = pj0[2];
        b1x = pj1[0]; b1y = pj1[1]; b1z = pj1[2];
    };

    auto accInit = [&](f32x4v (&acc)[8], int jt) {
        const float* tjB = t + (size_t)(b * N_ + jt * 16 + ln) * H_ + h4 * 4;
#pragma unroll
        for (int mf = 0; mf < 8; ++mf) {
            float4 tiv = *(const float4*)(tiS + mf * 64 + h4 * 16);
            float4 tj = *(const float4*)(tjB + mf * 16);
            acc[mf][0] = tiv.x + tj.x;
            acc[mf][1] = tiv.y + tj.y;
            acc[mf][2] = tiv.z + tj.z;
            acc[mf][3] = tiv.w + tj.w;
        }
    };

    auto phaseApass = [&](char* buf, int q, float bx, float by, float bz) {
        const int pq = q * 8 + pA8;
        float dotv = ax * bx + ay * by + az * bz;
        float cx = ay * bz - az * by;
        float cy = az * bx - ax * bz;
        float cz = ax * by - ay * bx;
        float cns = cx * cx + cy * cy + cz * cz;
        float cn = sqrtf(cns);
        float var = Saa * dotv * dotv + Sbb * cns + Scc +
                    2.f * (Sab * dotv * cn + Sac * dotv + Sbc * cn);
        float rstd = rsqrtf(var + LN_EPS);
        f16 d2 = (f16)(dotv * rstd), c2 = (f16)(cn * rstd), r2 = (f16)rstd;
        f16x2 D2 = {d2, d2}, C2 = {c2, c2}, R2 = {r2, r2};
        const f16x2 Z = {(f16)0.f, (f16)0.f};

        f16x2 vp0 = __builtin_elementwise_max(D2 * u2h(cagA.x) + (C2 * u2h(cbgA.x) + (R2 * u2h(ccgA.x) + u2h(vbA.x))), Z);
        f16x2 vp1 = __builtin_elementwise_max(D2 * u2h(cagA.y) + (C2 * u2h(cbgA.y) + (R2 * u2h(ccgA.y) + u2h(vbA.y))), Z);
        f16x2 vp2 = __builtin_elementwise_max(D2 * u2h(cagA.z) + (C2 * u2h(cbgA.z) + (R2 * u2h(ccgA.z) + u2h(vbA.z))), Z);
        f16x2 vp3 = __builtin_elementwise_max(D2 * u2h(cagA.w) + (C2 * u2h(cbgA.w) + (R2 * u2h(ccgA.w) + u2h(vbA.w))), Z);
        f16x2 vp4 = __builtin_elementwise_max(D2 * u2h(cagB.x) + (C2 * u2h(cbgB.x) + (R2 * u2h(ccgB.x) + u2h(vbB.x))), Z);
        f16x2 vp5 = __builtin_elementwise_max(D2 * u2h(cagB.y) + (C2 * u2h(cbgB.y) + (R2 * u2h(ccgB.y) + u2h(vbB.y))), Z);
        f16x2 vp6 = __builtin_elementwise_max(D2 * u2h(cagB.z) + (C2 * u2h(cbgB.z) + (R2 * u2h(ccgB.z) + u2h(vbB.z))), Z);
        f16x2 vp7 = __builtin_elementwise_max(D2 * u2h(cagB.w) + (C2 * u2h(cbgB.w) + (R2 * u2h(ccgB.w) + u2h(vbB.w))), Z);

        f16x4 q0 = __builtin_shufflevector(vp0, vp1, 0, 1, 2, 3);
        f16x4 q1 = __builtin_shufflevector(vp2, vp3, 0, 1, 2, 3);
        f16x4 q2 = __builtin_shufflevector(vp4, vp5, 0, 1, 2, 3);
        f16x4 q3 = __builtin_shufflevector(vp6, vp7, 0, 1, 2, 3);
        f16x8 o0 = __builtin_shufflevector(q0, q1, 0, 1, 2, 3, 4, 5, 6, 7);
        f16x8 o1 = __builtin_shufflevector(q2, q3, 0, 1, 2, 3, 4, 5, 6, 7);

        const int rb = pq * 256, sw = (pq & 7) << 4;
        *(f16x8*)(buf + rb + ((lA * 32) ^ sw)) = o0;
        *(f16x8*)(buf + rb + ((lA * 32 + 16) ^ sw)) = o1;
    };

    auto gemm = [&](f32x4v (&acc)[8], char* buf) {
#pragma unroll
        for (int kc = 0; kc < 4; ++kc) {
            f16x8 bF = *(const f16x8*)(buf + ln * 256 + ((kc * 64 + h4 * 16) ^ ((ln & 7) << 4)));
#pragma unroll
            for (int mf = 0; mf < 8; ++mf)
                acc[mf] = __builtin_amdgcn_mfma_f32_16x16x32_f16(aF[mf][kc], bF, acc[mf], 0, 0, 0);
        }
    };

    auto phaseC = [&](f32x4v (&acc)[8], int jt) {
        float part = 0.f;
#pragma unroll
        for (int mf = 0; mf < 8; ++mf) {
            float4 swv = *(const float4*)(swS + mf * 64 + h4 * 16);
            part += fmaxf(acc[mf][0], 0.f) * swv.x;
            part += fmaxf(acc[mf][1], 0.f) * swv.y;
            part += fmaxf(acc[mf][2], 0.f) * swv.z;
            part += fmaxf(acc[mf][3], 0.f) * swv.w;
        }
        part += __shfl_xor(part, 16);
        part += __shfl_xor(part, 32);
        if (h4 == 0) scoreRow[jt * 16 + ln] = part + sb2v;
    };

    f32x4v accP[8], accQ[8];
    float A0x, A0y, A0z, A1x, A1y, A1z;
    float B0x, B0y, B0z, B1x, B1y, B1z;

    // prologue: tile 0 staged
    prefPos(0, A0x, A0y, A0z, A1x, A1y, A1z);
    accInit(accP, 0);
    phaseApass(rht0, 0, A0x, A0y, A0z);
    phaseApass(rht0, 1, A1x, A1y, A1z);

#pragma unroll 1
    for (int jt = 0; jt < 24; jt += 2) {
        const int j1 = jt + 1;
        const int j2 = (jt + 2 < 24) ? (jt + 2) : 23;   // clamp: last stage is dead work
        // -- compute tile jt, stage tile j1 --
        prefPos(j1, B0x, B0y, B0z, B1x, B1y, B1z);
        accInit(accQ, j1);
        gemm(accP, rht0);
        phaseApass(rht1, 0, B0x, B0y, B0z);
        phaseApass(rht1, 1, B1x, B1y, B1z);
        phaseC(accP, jt);
        // -- compute tile j1, stage tile j2 --
        prefPos(j2, A0x, A0y, A0z, A1x, A1y, A1z);
        accInit(accP, j2);
        gemm(accQ, rht1);
        phaseApass(rht0, 0, A0x, A0y, A0z);
        phaseApass(rht0, 1, A1x, A1y, A1z);
        phaseC(accQ, j1);
    }
}

// -------------------- softmax reductions (deterministic trees) --------------------

__global__ void k_pmax(const float* __restrict__ scores, float* __restrict__ pmax) {
    int c = blockIdx.x, b = blockIdx.y;
    int tid = threadIdx.x;
    size_t base = (size_t)b * N_ * N_ + (size_t)c * 2048;
    float m = -1e30f;
#pragma unroll
    for (int s = 0; s < 8; ++s) m = fmaxf(m, scores[base + s * 256 + tid]);
    __shared__ float red[256];
    red[tid] = m;
    __syncthreads();
    for (int st = 128; st > 0; st >>= 1) {
        if (tid < st) red[tid] = fmaxf(red[tid], red[tid + st]);
        __syncthreads();
    }
    if (tid == 0) pmax[b * NCHUNK + c] = red[0];
}

__global__ void k_psum(const float* __restrict__ scores, const float* __restrict__ pmax,
                       float* __restrict__ psum) {
    int c = blockIdx.x, b = blockIdx.y;
    int tid = threadIdx.x;
    __shared__ float gm;
    __shared__ float red[256];
    if (tid == 0) {
        float m = -1e30f;
        for (int k = 0; k < NCHUNK; ++k) m = fmaxf(m, pmax[b * NCHUNK + k]);
        gm = m;
    }
    __syncthreads();
    size_t base = (size_t)b * N_ * N_ + (size_t)c * 2048;
    float s = 0.f;
#pragma unroll
    for (int k = 0; k < 8; ++k) s += expf(scores[base + k * 256 + tid] - gm);
    red[tid] = s;
    __syncthreads();
    for (int st = 128; st > 0; st >>= 1) {
        if (tid < st) red[tid] += red[tid + st];
        __syncthreads();
    }
    if (tid == 0) psum[b * NCHUNK + c] = red[0];
}

// normalize scores -> att in place (one block per (b,i) row)
__global__ void k_att(float* __restrict__ scores, const float* __restrict__ pmax,
                      const float* __restrict__ psum) {
    int i = blockIdx.x, b = blockIdx.y;
    int tid = threadIdx.x;   // 384
    __shared__ float gm, gs;
    if (tid == 0) {
        float m = -1e30f;
        for (int k = 0; k < NCHUNK; ++k) m = fmaxf(m, pmax[b * NCHUNK + k]);
        gm = m;
    } else if (tid == 1) {
        float s = 0.f;
        for (int k = 0; k < NCHUNK; ++k) s += psum[b * NCHUNK + k];
        gs = s;
    }
    __syncthreads();
    size_t idx = (size_t)(b * N_ + i) * N_ + tid;
    scores[idx] = expf(scores[idx] - gm) / gs;
}

// -------------------- phase 2: x (algebraic LN, fp32 coeffs) --------------------
// One block per (b,i). accH = sum att*relu_h (via algebraic LN, no reductions),
// accI = sum att*in_j, s = sum att. x = 0.5*(accH@vW2 + s*vb2) + 0.25*(s*in_i + accI)
__global__ __launch_bounds__(256) void k_x(
    const float* __restrict__ inp, const float* __restrict__ pos,
    const float* __restrict__ coeffF, const float* __restrict__ scal,
    const float* __restrict__ vbeta, const float* __restrict__ vW2,
    const float* __restrict__ vb2, const float* __restrict__ att,
    float* __restrict__ xout) {
    int i = blockIdx.x, b = blockIdx.y;
    int tid = threadIdx.x;
    int jsub = tid >> 3, dg = tid & 7;

    __shared__ float accH[32 * 128];
    __shared__ float accI[32 * 64];
    __shared__ float accS[32];

    float cA[16], cB[16], cC[16], vB[16];
#pragma unroll
    for (int dd = 0; dd < 16; ++dd) {
        int d = dg * 16 + dd;
        cA[dd] = coeffF[d]; cB[dd] = coeffF[128 + d];
        cC[dd] = coeffF[256 + d]; vB[dd] = vbeta[d];
    }
    const float Saa = scal[0], Sbb = scal[1], Scc = scal[2];
    const float Sab = scal[3], Sac = scal[4], Sbc = scal[5];

    float aH[16];
    float aI[8];
#pragma unroll
    for (int dd = 0; dd < 16; ++dd) aH[dd] = 0.f;
#pragma unroll
    for (int ff = 0; ff < 8; ++ff) aI[ff] = 0.f;
    float aS = 0.f;

    const float* pi = pos + (size_t)(b * N_ + i) * 3;
    float ax = pi[0], ay = pi[1], az = pi[2];

    for (int jc = 0; jc < 12; ++jc) {
        int j = jc * 32 + jsub;
        const float* pj = pos + (size_t)(b * N_ + j) * 3;
        float bx = pj[0], by = pj[1], bz = pj[2];
        float dotv = ax * bx + ay * by + az * bz;
        float cx = ay * bz - az * by;
        float cy = az * bx - ax * bz;
        float cz = ax * by - ay * bx;
        float cns = cx * cx + cy * cy + cz * cz;
        float cn = sqrtf(cns);
        float a = att[(size_t)(b * N_ + i) * N_ + j];

        float var = Saa * dotv * dotv + Sbb * cns + Scc +
                    2.f * (Sab * dotv * cn + Sac * dotv + Sbc * cn);
        float rstd = rsqrtf(var + LN_EPS);
        float dr = dotv * rstd, cr = cn * rstd;
#pragma unroll
        for (int dd = 0; dd < 16; ++dd) {
            float v = fmaf(dr, cA[dd], fmaf(cr, cB[dd], fmaf(rstd, cC[dd], vB[dd])));
            aH[dd] = fmaf(a, fmaxf(v, 0.f), aH[dd]);
        }
#pragma unroll
        for (int ff = 0; ff < 8; ++ff) {
            int f = dg * 8 + ff;
            aI[ff] = fmaf(a, inp[(size_t)(b * N_ + j) * F_ + f], aI[ff]);
        }
        if (dg == 0) aS += a;
    }

#pragma unroll
    for (int dd = 0; dd < 16; ++dd) accH[jsub * 128 + dg * 16 + dd] = aH[dd];
#pragma unroll
    for (int ff = 0; ff < 8; ++ff) accI[jsub * 64 + dg * 8 + ff] = aI[ff];
    if (dg == 0) accS[jsub] = aS;
    __syncthreads();

    for (int st = 16; st > 0; st >>= 1) {
        if (jsub < st) {
#pragma unroll
            for (int dd = 0; dd < 16; ++dd)
                accH[jsub * 128 + dg * 16 + dd] += accH[(jsub + st) * 128 + dg * 16 + dd];
#pragma unroll
            for (int ff = 0; ff < 8; ++ff)
                accI[jsub * 64 + dg * 8 + ff] += accI[(jsub + st) * 64 + dg * 8 + ff];
            if (dg == 0) accS[jsub] += accS[jsub + st];
        }
        __syncthreads();
    }

    if (tid < F_) {
        int f = tid;
        float s = accS[0];
        float xv = 0.f;
#pragma unroll
        for (int d = 0; d < H_; ++d) xv = fmaf(accH[d], vW2[d * F_ + f], xv);
        float r = 0.5f * (xv + s * vb2[f]) +
                  0.25f * (s * inp[(size_t)(b * N_ + i) * F_ + f] + accI[f]);
        xout[(size_t)(b * N_ + i) * F_ + f] = r;
    }
}

// -------------------- launch --------------------

extern "C" void kernel_launch(void* const* d_in, const int* in_sizes, int n_in,
                              void* d_out, int out_size, void* d_ws, size_t ws_size,
                              hipStream_t stream) {
    const float* inp   = (const float*)d_in[0];
    const float* pos   = (const float*)d_in[1];
    const float* vW1   = (const float*)d_in[2];
    const float* vb1   = (const float*)d_in[3];
    const float* vg    = (const float*)d_in[4];
    const float* vbeta = (const float*)d_in[5];
    const float* vW2   = (const float*)d_in[6];
    const float* vb2   = (const float*)d_in[7];
    const float* sW1   = (const float*)d_in[8];
    const float* sb1   = (const float*)d_in[9];
    const float* sW2   = (const float*)d_in[10];
    const float* sb2   = (const float*)d_in[11];

    float* xout   = (float*)d_out;                 // B*N*F
    float* attout = xout + B_ * N_ * F_;           // B*N*N (scores -> att in place)

    unsigned short* W2hT   = (unsigned short*)d_ws;                  // 32KB fp16
    unsigned int*   coeffP = (unsigned int*)((char*)d_ws + 32768);   // 1KB packed f16x2
    float*          scal   = (float*)((char*)d_ws + 33792);          // 6 scalars
    float*          coeffF = (float*)((char*)d_ws + 34816);          // 3x128 fp32
    float* t    = (float*)((char*)d_ws + 36864);                     // B*N*128 fp32
    float* pmax = t + B_ * N_ * H_;                                  // B*72
    float* psum = pmax + B_ * NCHUNK;                                // B*72

    k_prep_w2p<<<64, 256, 0, stream>>>(vW2, sW1, W2hT);
    k_prep_coeff<<<1, 128, 0, stream>>>(vW1, vb1, vg, vbeta, coeffP, scal, coeffF);
    k_prep_t<<<B_ * N_, 128, 0, stream>>>(inp, sW1, vb2, sb1, t);
    k_scores<<<dim3(96, B_), 256, 0, stream>>>(
        pos, coeffP, scal, W2hT, t, sW2, sb2, attout);
    k_pmax<<<dim3(NCHUNK, B_), 256, 0, stream>>>(attout, pmax);
    k_psum<<<dim3(NCHUNK, B_), 256, 0, stream>>>(attout, pmax, psum);
    k_att<<<dim3(N_, B_), 384, 0, stream>>>(attout, pmax, psum);
    k_x<<<dim3(N_, B_), 256, 0, stream>>>(inp, pos, coeffF, scal, vbeta, vW2, vb2,
                                          attout, xout);
}

// Round 10
// 213.936 us; speedup vs baseline: 4.4767x; 1.0223x over previous
//
#include <hip/hip_runtime.h>
#include <hip/hip_bf16.h>
#include <math.h>

#define B_ 8
#define N_ 384
#define F_ 64
#define H_ 128
#define LN_EPS 1e-5f

typedef _Float16 f16;
typedef f16 f16x2 __attribute__((ext_vector_type(2)));
typedef f16 f16x4 __attribute__((ext_vector_type(4)));
typedef f16 f16x8 __attribute__((ext_vector_type(8)));
typedef float f32x4v __attribute__((ext_vector_type(4)));

static __device__ __forceinline__ f16x2 u2h(unsigned int u) {
    union { unsigned int u; f16x2 h; } c; c.u = u; return c.h;
}

// -------------------- setup kernels --------------------

// W2hT[n][k] = fp16( 0.5 * sum_f vW2[k,f] * sW1[f,n] )   (128x128, TRANSPOSED for MFMA A)
__global__ void k_prep_w2p(const float* __restrict__ vW2, const float* __restrict__ sW1,
                           unsigned short* __restrict__ W2hT) {
    int idx = blockIdx.x * 256 + threadIdx.x;   // 0..16383
    int k = idx >> 7, n = idx & 127;
    float acc = 0.f;
#pragma unroll
    for (int f = 0; f < F_; ++f) acc = fmaf(vW2[k * F_ + f], sW1[f * H_ + n], acc);
    f16 hv = (f16)(0.5f * acc);
    W2hT[n * H_ + k] = *reinterpret_cast<unsigned short*>(&hv);
}

// t[row][n] = sum_f (0.25*(in[row,f]+vb2[f])) * sW1[f,n] + 0.5*sb1[n]
__global__ void k_prep_t(const float* __restrict__ inp, const float* __restrict__ sW1,
                         const float* __restrict__ vb2, const float* __restrict__ sb1,
                         float* __restrict__ t) {
    int row = blockIdx.x;
    int n = threadIdx.x;
    float acc = 0.f;
#pragma unroll
    for (int f = 0; f < F_; ++f)
        acc = fmaf(0.25f * (inp[row * F_ + f] + vb2[f]), sW1[f * H_ + n], acc);
    t[row * H_ + n] = acc + 0.5f * sb1[n];
}

// Algebraic-LN coefficients: centered ca/cb/cc (·vg) as packed f16 (k_scores) and
// fp32 (k_x), + 6 covariance scalars.
__global__ void k_prep_coeff(const float* __restrict__ vW1, const float* __restrict__ vb1,
                             const float* __restrict__ vg, const float* __restrict__ vbeta,
                             unsigned int* __restrict__ coeffP, float* __restrict__ scal,
                             float* __restrict__ coeffF) {
    __shared__ float red[128];
    __shared__ float caS[128], cbS[128], ccS[128];
    const int d = threadIdx.x;   // 128
    float a = vW1[d], bb = vW1[H_ + d], c = vb1[d];

    float mA, mB, mC, Saa, Sbb, Scc, Sab, Sac, Sbc;
    float ca, cb, cc;
#define BMEAN(OUT, VAL)                                                  \
    red[d] = (VAL); __syncthreads();                                     \
    for (int st = 64; st > 0; st >>= 1) {                                \
        if (d < st) red[d] += red[d + st];                               \
        __syncthreads();                                                 \
    }                                                                    \
    OUT = red[0] * (1.f / 128.f); __syncthreads();

    BMEAN(mA, a); BMEAN(mB, bb); BMEAN(mC, c);
    ca = a - mA; cb = bb - mB; cc = c - mC;
    caS[d] = ca * vg[d]; cbS[d] = cb * vg[d]; ccS[d] = cc * vg[d];
    BMEAN(Saa, ca * ca); BMEAN(Sbb, cb * cb); BMEAN(Scc, cc * cc);
    BMEAN(Sab, ca * cb); BMEAN(Sac, ca * cc); BMEAN(Sbc, cb * cc);
#undef BMEAN
    __syncthreads();
    coeffF[d] = caS[d]; coeffF[128 + d] = cbS[d]; coeffF[256 + d] = ccS[d];
    if (d < 64) {
        int d0 = 2 * d;
        union { f16x2 h; unsigned int u; } cv;
        cv.h = (f16x2){(f16)caS[d0], (f16)caS[d0 + 1]};   coeffP[d]       = cv.u;
        cv.h = (f16x2){(f16)cbS[d0], (f16)cbS[d0 + 1]};   coeffP[64 + d]  = cv.u;
        cv.h = (f16x2){(f16)ccS[d0], (f16)ccS[d0 + 1]};   coeffP[128 + d] = cv.u;
        cv.h = (f16x2){(f16)vbeta[d0], (f16)vbeta[d0 + 1]}; coeffP[192 + d] = cv.u;
    }
    if (d == 0) {
        scal[0] = Saa; scal[1] = Sbb; scal[2] = Scc;
        scal[3] = Sab; scal[4] = Sac; scal[5] = Sbc;
    }
}

// -------------------- phase 1: scores (pipelined) + per-row softmax stats --------------------
// Block = 4 waves; wave w owns i-row blockIdx.x*4+w; 24 j-tiles of 16 pairs, barrier-free.
// Cross-tile software pipeline (double-buffered rht). A-frags of W' resident in 128 VGPR.
// Epilogue: online (rowmax, rowsum=sum exp(s-rowmax)) per row -> ws, replacing the
// 3-pass softmax kernels.
// __launch_bounds__(256) only — min-waves arg caps VGPR at 256/arg => spills (R5/R6).
__global__ __launch_bounds__(256) void k_scores(
    const float* __restrict__ pos, const unsigned int* __restrict__ coeffP,
    const float* __restrict__ scal, const unsigned short* __restrict__ W2hT,
    const float* __restrict__ t, const float* __restrict__ sW2,
    const float* __restrict__ sb2, float* __restrict__ scores,
    float* __restrict__ rowmax, float* __restrict__ rowsum) {
    __shared__ __align__(16) char smem[36864];   // 4w x (4KB rht0 + 4KB rht1) + 4x512 ti + 4x512 sW2

    const int tid = threadIdx.x;
    const int b = blockIdx.y;
    const int w = tid >> 6, lane = tid & 63;
    const int i = blockIdx.x * 4 + w;
    const int ln = lane & 15, h4 = lane >> 4;

    char* rht0 = smem + w * 8192;
    char* rht1 = rht0 + 4096;
    char* tiS = smem + 32768 + w * 512;
    char* swS = smem + 34816 + w * 512;

    // stage wave-private ti and sW2 copies (same-wave ordering, no barrier)
    if (lane < 32) {
        *(float4*)(tiS + lane * 16) = *(const float4*)(t + (size_t)(b * N_ + i) * H_ + lane * 4);
        *(float4*)(swS + lane * 16) = *(const float4*)(sW2 + lane * 4);
    }

    // A-fragments resident (128 VGPR)
    f16x8 aF[8][4];
#pragma unroll
    for (int mf = 0; mf < 8; ++mf)
#pragma unroll
        for (int kc = 0; kc < 4; ++kc)
            aF[mf][kc] = *(const f16x8*)(W2hT + (mf * 16 + ln) * H_ + kc * 32 + h4 * 8);

    // phase-A per-lane coeffs: lA = lane&7 -> dims lA*16..+15 (packed f16x2)
    const int lA = lane & 7;
    const uint4 cagA = *(const uint4*)(coeffP + lA * 8);
    const uint4 cagB = *(const uint4*)(coeffP + lA * 8 + 4);
    const uint4 cbgA = *(const uint4*)(coeffP + 64 + lA * 8);
    const uint4 cbgB = *(const uint4*)(coeffP + 64 + lA * 8 + 4);
    const uint4 ccgA = *(const uint4*)(coeffP + 128 + lA * 8);
    const uint4 ccgB = *(const uint4*)(coeffP + 128 + lA * 8 + 4);
    const uint4 vbA  = *(const uint4*)(coeffP + 192 + lA * 8);
    const uint4 vbB  = *(const uint4*)(coeffP + 192 + lA * 8 + 4);

    const float Saa = scal[0], Sbb = scal[1], Scc = scal[2];
    const float Sab = scal[3], Sac = scal[4], Sbc = scal[5];
    const float sb2v = sb2[0];

    const float* pi = pos + (size_t)(b * N_ + i) * 3;
    const float ax = pi[0], ay = pi[1], az = pi[2];
    const int pA8 = lane >> 3;   // phase-A pair-within-pass

    float* scoreRow = scores + (size_t)(b * N_ + i) * N_;

    float m_run = -1e30f, s_run = 0.f;   // online row softmax stats

    auto prefPos = [&](int jt, float& b0x, float& b0y, float& b0z,
                       float& b1x, float& b1y, float& b1z) {
        const float* pj0 = pos + (size_t)(b * N_ + jt * 16 + pA8) * 3;
        const float* pj1 = pj0 + 24;   // +8 rows * 3
        b0x = pj0[0]; b0y = pj0[1]; b0z = pj0[2];
        b1x = pj1[0]; b1y = pj1[1]; b1z = pj1[2];
    };

    auto accInit = [&](f32x4v (&acc)[8], int jt) {
        const float* tjB = t + (size_t)(b * N_ + jt * 16 + ln) * H_ + h4 * 4;
#pragma unroll
        for (int mf = 0; mf < 8; ++mf) {
            float4 tiv = *(const float4*)(tiS + mf * 64 + h4 * 16);
            float4 tj = *(const float4*)(tjB + mf * 16);
            acc[mf][0] = tiv.x + tj.x;
            acc[mf][1] = tiv.y + tj.y;
            acc[mf][2] = tiv.z + tj.z;
            acc[mf][3] = tiv.w + tj.w;
        }
    };

    auto phaseApass = [&](char* buf, int q, float bx, float by, float bz) {
        const int pq = q * 8 + pA8;
        float dotv = ax * bx + ay * by + az * bz;
        float cx = ay * bz - az * by;
        float cy = az * bx - ax * bz;
        float cz = ax * by - ay * bx;
        float cns = cx * cx + cy * cy + cz * cz;
        float cn = sqrtf(cns);
        float var = Saa * dotv * dotv + Sbb * cns + Scc +
                    2.f * (Sab * dotv * cn + Sac * dotv + Sbc * cn);
        float rstd = rsqrtf(var + LN_EPS);
        f16 d2 = (f16)(dotv * rstd), c2 = (f16)(cn * rstd), r2 = (f16)rstd;
        f16x2 D2 = {d2, d2}, C2 = {c2, c2}, R2 = {r2, r2};
        const f16x2 Z = {(f16)0.f, (f16)0.f};

        f16x2 vp0 = __builtin_elementwise_max(D2 * u2h(cagA.x) + (C2 * u2h(cbgA.x) + (R2 * u2h(ccgA.x) + u2h(vbA.x))), Z);
        f16x2 vp1 = __builtin_elementwise_max(D2 * u2h(cagA.y) + (C2 * u2h(cbgA.y) + (R2 * u2h(ccgA.y) + u2h(vbA.y))), Z);
        f16x2 vp2 = __builtin_elementwise_max(D2 * u2h(cagA.z) + (C2 * u2h(cbgA.z) + (R2 * u2h(ccgA.z) + u2h(vbA.z))), Z);
        f16x2 vp3 = __builtin_elementwise_max(D2 * u2h(cagA.w) + (C2 * u2h(cbgA.w) + (R2 * u2h(ccgA.w) + u2h(vbA.w))), Z);
        f16x2 vp4 = __builtin_elementwise_max(D2 * u2h(cagB.x) + (C2 * u2h(cbgB.x) + (R2 * u2h(ccgB.x) + u2h(vbB.x))), Z);
        f16x2 vp5 = __builtin_elementwise_max(D2 * u2h(cagB.y) + (C2 * u2h(cbgB.y) + (R2 * u2h(ccgB.y) + u2h(vbB.y))), Z);
        f16x2 vp6 = __builtin_elementwise_max(D2 * u2h(cagB.z) + (C2 * u2h(cbgB.z) + (R2 * u2h(ccgB.z) + u2h(vbB.z))), Z);
        f16x2 vp7 = __builtin_elementwise_max(D2 * u2h(cagB.w) + (C2 * u2h(cbgB.w) + (R2 * u2h(ccgB.w) + u2h(vbB.w))), Z);

        f16x4 q0 = __builtin_shufflevector(vp0, vp1, 0, 1, 2, 3);
        f16x4 q1 = __builtin_shufflevector(vp2, vp3, 0, 1, 2, 3);
        f16x4 q2 = __builtin_shufflevector(vp4, vp5, 0, 1, 2, 3);
        f16x4 q3 = __builtin_shufflevector(vp6, vp7, 0, 1, 2, 3);
        f16x8 o0 = __builtin_shufflevector(q0, q1, 0, 1, 2, 3, 4, 5, 6, 7);
        f16x8 o1 = __builtin_shufflevector(q2, q3, 0, 1, 2, 3, 4, 5, 6, 7);

        const int rb = pq * 256, sw = (pq & 7) << 4;
        *(f16x8*)(buf + rb + ((lA * 32) ^ sw)) = o0;
        *(f16x8*)(buf + rb + ((lA * 32 + 16) ^ sw)) = o1;
    };

    auto gemm = [&](f32x4v (&acc)[8], char* buf) {
#pragma unroll
        for (int kc = 0; kc < 4; ++kc) {
            f16x8 bF = *(const f16x8*)(buf + ln * 256 + ((kc * 64 + h4 * 16) ^ ((ln & 7) << 4)));
#pragma unroll
            for (int mf = 0; mf < 8; ++mf)
                acc[mf] = __builtin_amdgcn_mfma_f32_16x16x32_f16(aF[mf][kc], bF, acc[mf], 0, 0, 0);
        }
    };

    auto phaseC = [&](f32x4v (&acc)[8], int jt) {
        float part = 0.f;
#pragma unroll
        for (int mf = 0; mf < 8; ++mf) {
            float4 swv = *(const float4*)(swS + mf * 64 + h4 * 16);
            part += fmaxf(acc[mf][0], 0.f) * swv.x;
            part += fmaxf(acc[mf][1], 0.f) * swv.y;
            part += fmaxf(acc[mf][2], 0.f) * swv.z;
            part += fmaxf(acc[mf][3], 0.f) * swv.w;
        }
        part += __shfl_xor(part, 16);
        part += __shfl_xor(part, 32);
        float sc = part + sb2v;
        if (h4 == 0) scoreRow[jt * 16 + ln] = sc;
        // online row stats (identical across h4 replicas)
        float mn = fmaxf(m_run, sc);
        s_run = s_run * expf(m_run - mn) + expf(sc - mn);
        m_run = mn;
    };

    f32x4v accP[8], accQ[8];
    float A0x, A0y, A0z, A1x, A1y, A1z;
    float B0x, B0y, B0z, B1x, B1y, B1z;

    // prologue: tile 0 staged
    prefPos(0, A0x, A0y, A0z, A1x, A1y, A1z);
    accInit(accP, 0);
    phaseApass(rht0, 0, A0x, A0y, A0z);
    phaseApass(rht0, 1, A1x, A1y, A1z);

#pragma unroll 1
    for (int jt = 0; jt < 24; jt += 2) {
        const int j1 = jt + 1;
        const int j2 = (jt + 2 < 24) ? (jt + 2) : 23;   // clamp: last stage is dead work
        // -- compute tile jt, stage tile j1 --
        prefPos(j1, B0x, B0y, B0z, B1x, B1y, B1z);
        accInit(accQ, j1);
        gemm(accP, rht0);
        phaseApass(rht1, 0, B0x, B0y, B0z);
        phaseApass(rht1, 1, B1x, B1y, B1z);
        phaseC(accP, jt);
        // -- compute tile j1, stage tile j2 --
        prefPos(j2, A0x, A0y, A0z, A1x, A1y, A1z);
        accInit(accP, j2);
        gemm(accQ, rht1);
        phaseApass(rht0, 0, A0x, A0y, A0z);
        phaseApass(rht0, 1, A1x, A1y, A1z);
        phaseC(accQ, j1);
    }

    // row-stat reduce across ln (h4 replicas identical), fixed shuffle tree
#pragma unroll
    for (int d = 1; d < 16; d <<= 1) {
        float mo = __shfl_xor(m_run, d);
        float so = __shfl_xor(s_run, d);
        float mn = fmaxf(m_run, mo);
        s_run = s_run * expf(m_run - mn) + so * expf(mo - mn);
        m_run = mn;
    }
    if (lane == 0) {
        rowmax[b * N_ + i] = m_run;
        rowsum[b * N_ + i] = s_run;
    }
}

// -------------------- per-batch softmax reduce: rowscale_i = exp(rmax_i-gmax)/total ----------
__global__ void k_gred(const float* __restrict__ rowmax, const float* __restrict__ rowsum,
                       float* __restrict__ rowscale) {
    int b = blockIdx.x, tid = threadIdx.x;   // 512
    __shared__ float mred[512], sred[512];
    float m = (tid < N_) ? rowmax[b * N_ + tid] : -1e30f;
    float s = (tid < N_) ? rowsum[b * N_ + tid] : 0.f;
    mred[tid] = m;
    __syncthreads();
    for (int st = 256; st > 0; st >>= 1) {
        if (tid < st) mred[tid] = fmaxf(mred[tid], mred[tid + st]);
        __syncthreads();
    }
    float gm = mred[0];
    sred[tid] = s * expf(m - gm);
    __syncthreads();
    for (int st = 256; st > 0; st >>= 1) {
        if (tid < st) sred[tid] += sred[tid + st];
        __syncthreads();
    }
    float inv = 1.f / sred[0];
    if (tid < N_) rowscale[b * N_ + tid] = expf(m - gm) * inv;
}

// -------------------- phase 2: x (algebraic LN) + fused att normalize/write ----------
// One block per (b,i). Reads raw scores, a = exp(s-rmax_i)*rowscale_i; writes att
// in place (same-wave read-before-write per element); accH/accI/s accumulation as before.
__global__ __launch_bounds__(256) void k_x(
    const float* __restrict__ inp, const float* __restrict__ pos,
    const float* __restrict__ coeffF, const float* __restrict__ scal,
    const float* __restrict__ vbeta, const float* __restrict__ vW2,
    const float* __restrict__ vb2, float* __restrict__ scoresAtt,
    const float* __restrict__ rowmax, const float* __restrict__ rowscale,
    float* __restrict__ xout) {
    int i = blockIdx.x, b = blockIdx.y;
    int tid = threadIdx.x;
    int jsub = tid >> 3, dg = tid & 7;

    __shared__ float accH[32 * 128];
    __shared__ float accI[32 * 64];
    __shared__ float accS[32];

    float cA[16], cB[16], cC[16], vB[16];
#pragma unroll
    for (int dd = 0; dd < 16; ++dd) {
        int d = dg * 16 + dd;
        cA[dd] = coeffF[d]; cB[dd] = coeffF[128 + d];
        cC[dd] = coeffF[256 + d]; vB[dd] = vbeta[d];
    }
    const float Saa = scal[0], Sbb = scal[1], Scc = scal[2];
    const float Sab = scal[3], Sac = scal[4], Sbc = scal[5];
    const float rmaxI = rowmax[b * N_ + i];
    const float rscaleI = rowscale[b * N_ + i];

    float aH[16];
    float aI[8];
#pragma unroll
    for (int dd = 0; dd < 16; ++dd) aH[dd] = 0.f;
#pragma unroll
    for (int ff = 0; ff < 8; ++ff) aI[ff] = 0.f;
    float aS = 0.f;

    const float* pi = pos + (size_t)(b * N_ + i) * 3;
    float ax = pi[0], ay = pi[1], az = pi[2];

    for (int jc = 0; jc < 12; ++jc) {
        int j = jc * 32 + jsub;
        const float* pj = pos + (size_t)(b * N_ + j) * 3;
        float bx = pj[0], by = pj[1], bz = pj[2];
        float dotv = ax * bx + ay * by + az * bz;
        float cx = ay * bz - az * by;
        float cy = az * bx - ax * bz;
        float cz = ax * by - ay * bx;
        float cns = cx * cx + cy * cy + cz * cz;
        float cn = sqrtf(cns);

        size_t sidx = (size_t)(b * N_ + i) * N_ + j;
        float sc = scoresAtt[sidx];
        float a = expf(sc - rmaxI) * rscaleI;
        if (dg == 0) scoresAtt[sidx] = a;   // same-wave: all 8 readers read before this write

        float var = Saa * dotv * dotv + Sbb * cns + Scc +
                    2.f * (Sab * dotv * cn + Sac * dotv + Sbc * cn);
        float rstd = rsqrtf(var + LN_EPS);
        float dr = dotv * rstd, cr = cn * rstd;
#pragma unroll
        for (int dd = 0; dd < 16; ++dd) {
            float v = fmaf(dr, cA[dd], fmaf(cr, cB[dd], fmaf(rstd, cC[dd], vB[dd])));
            aH[dd] = fmaf(a, fmaxf(v, 0.f), aH[dd]);
        }
#pragma unroll
        for (int ff = 0; ff < 8; ++ff) {
            int f = dg * 8 + ff;
            aI[ff] = fmaf(a, inp[(size_t)(b * N_ + j) * F_ + f], aI[ff]);
        }
        if (dg == 0) aS += a;
    }

#pragma unroll
    for (int dd = 0; dd < 16; ++dd) accH[jsub * 128 + dg * 16 + dd] = aH[dd];
#pragma unroll
    for (int ff = 0; ff < 8; ++ff) accI[jsub * 64 + dg * 8 + ff] = aI[ff];
    if (dg == 0) accS[jsub] = aS;
    __syncthreads();

    for (int st = 16; st > 0; st >>= 1) {
        if (jsub < st) {
#pragma unroll
            for (int dd = 0; dd < 16; ++dd)
                accH[jsub * 128 + dg * 16 + dd] += accH[(jsub + st) * 128 + dg * 16 + dd];
#pragma unroll
            for (int ff = 0; ff < 8; ++ff)
                accI[jsub * 64 + dg * 8 + ff] += accI[(jsub + st) * 64 + dg * 8 + ff];
            if (dg == 0) accS[jsub] += accS[jsub + st];
        }
        __syncthreads();
    }

    if (tid < F_) {
        int f = tid;
        float s = accS[0];
        float xv = 0.f;
#pragma unroll
        for (int d = 0; d < H_; ++d) xv = fmaf(accH[d], vW2[d * F_ + f], xv);
        float r = 0.5f * (xv + s * vb2[f]) +
                  0.25f * (s * inp[(size_t)(b * N_ + i) * F_ + f] + accI[f]);
        xout[(size_t)(b * N_ + i) * F_ + f] = r;
    }
}

// -------------------- launch --------------------

extern "C" void kernel_launch(void* const* d_in, const int* in_sizes, int n_in,
                              void* d_out, int out_size, void* d_ws, size_t ws_size,
                              hipStream_t stream) {
    const float* inp   = (const float*)d_in[0];
    const float* pos   = (const float*)d_in[1];
    const float* vW1   = (const float*)d_in[2];
    const float* vb1   = (const float*)d_in[3];
    const float* vg    = (const float*)d_in[4];
    const float* vbeta = (const float*)d_in[5];
    const float* vW2   = (const float*)d_in[6];
    const float* vb2   = (const float*)d_in[7];
    const float* sW1   = (const float*)d_in[8];
    const float* sb1   = (const float*)d_in[9];
    const float* sW2   = (const float*)d_in[10];
    const float* sb2   = (const float*)d_in[11];

    float* xout   = (float*)d_out;                 // B*N*F
    float* attout = xout + B_ * N_ * F_;           // B*N*N (scores -> att in place)

    unsigned short* W2hT   = (unsigned short*)d_ws;                  // 32KB fp16
    unsigned int*   coeffP = (unsigned int*)((char*)d_ws + 32768);   // 1KB packed f16x2
    float*          scal   = (float*)((char*)d_ws + 33792);          // 6 scalars
    float*          coeffF = (float*)((char*)d_ws + 34816);          // 3x128 fp32
    float* t       = (float*)((char*)d_ws + 36864);                  // B*N*128 fp32
    float* rowmax  = t + B_ * N_ * H_;                               // B*N
    float* rowsum  = rowmax + B_ * N_;                               // B*N
    float* rowscale= rowsum + B_ * N_;                               // B*N

    k_prep_w2p<<<64, 256, 0, stream>>>(vW2, sW1, W2hT);
    k_prep_coeff<<<1, 128, 0, stream>>>(vW1, vb1, vg, vbeta, coeffP, scal, coeffF);
    k_prep_t<<<B_ * N_, 128, 0, stream>>>(inp, sW1, vb2, sb1, t);
    k_scores<<<dim3(96, B_), 256, 0, stream>>>(
        pos, coeffP, scal, W2hT, t, sW2, sb2, attout, rowmax, rowsum);
    k_gred<<<B_, 512, 0, stream>>>(rowmax, rowsum, rowscale);
    k_x<<<dim3(N_, B_), 256, 0, stream>>>(inp, pos, coeffF, scal, vbeta, vW2, vb2,
                                          attout, rowmax, rowscale, xout);
}